// Round 3
// baseline (768.593 us; speedup 1.0000x reference)
//
#include <hip/hip_runtime.h>
#include <math.h>

#define N_NODES 50000
#define N_EDGES 800000
#define HDIM 128

typedef __attribute__((ext_vector_type(8))) short bf16x8;
typedef __attribute__((ext_vector_type(4))) float floatx4;

__device__ __forceinline__ unsigned f2bf_u(float f) {
    union { float f; unsigned u; } x; x.f = f;
    return (x.u + 0x7FFFu + ((x.u >> 16) & 1u)) >> 16;
}
__device__ __forceinline__ short f2bf(float f) { return (short)f2bf_u(f); }
__device__ __forceinline__ float silu_f(float v) { return v / (1.0f + __expf(-v)); }

// async 16B/lane global->LDS DMA; lds base is wave-uniform, HW adds lane*16.
__device__ __forceinline__ void gl_lds16(const void* g, void* l) {
    __builtin_amdgcn_global_load_lds(
        (const __attribute__((address_space(1))) unsigned int*)g,
        (__attribute__((address_space(3))) unsigned int*)l, 16, 0, 0);
}

// Swizzled LDS index for the 128x128 bf16 activation buffer (C-write + A-read
// both conflict-free; verified round 2).
__device__ __forceinline__ int sT_idx(int row, int c) {
    int kb = (c >> 3) ^ ((row >> 1) & 7);
    return row * 128 + kb * 8 + (c & 7);
}

// ---- weight packing: W (K x 128 fp32, k-major) -> bf16 MFMA B-frag order ----
__global__ void pack_w_kernel(const float* __restrict__ W, short* __restrict__ dst,
                              int K, int total) {
    int t = blockIdx.x * 256 + threadIdx.x;
    if (t >= total) return;
    int lane = t & 63;
    int ctk = t >> 6;
    int ct = ctk & 7, kc = ctk >> 3;
    int c = ct * 16 + (lane & 15);
    int kb = kc * 32 + (lane >> 4) * 8;
    bf16x8 v;
#pragma unroll
    for (int j = 0; j < 8; ++j) {
        int k = kb + j;
        v[j] = (k < K) ? f2bf(W[(size_t)k * HDIM + c]) : (short)0;
    }
    *(bf16x8*)&dst[(size_t)t * 8] = v;
}

// ---- fp32 -> bf16 row-major pack (h) ----
__global__ void pack_bf16_kernel(const float* __restrict__ src, short* __restrict__ dst,
                                 int n8) {
    int t = blockIdx.x * 256 + threadIdx.x;
    if (t >= n8) return;
    const float4* p = (const float4*)(src + (size_t)t * 8);
    float4 a = p[0], b = p[1];
    uint4 o;
    o.x = f2bf_u(a.x) | (f2bf_u(a.y) << 16);
    o.y = f2bf_u(a.z) | (f2bf_u(a.w) << 16);
    o.z = f2bf_u(b.x) | (f2bf_u(b.y) << 16);
    o.w = f2bf_u(b.z) | (f2bf_u(b.w) << 16);
    *(uint4*)(dst + (size_t)t * 8) = o;
}

__global__ __launch_bounds__(256, 4)
void egnn_edge_mfma(const short* __restrict__ h_bf, const float* __restrict__ x,
                    const int* __restrict__ ei, const float* __restrict__ ea,
                    const short* __restrict__ pWe1, const short* __restrict__ pWe2,
                    const short* __restrict__ pWx1,
                    const float* __restrict__ be1, const float* __restrict__ be2,
                    const float* __restrict__ bx1, const float* __restrict__ Wx2,
                    const float* __restrict__ bx2,
                    float* __restrict__ agg, float* __restrict__ dxb) {
    // sT doubles as the layer-1 staging double-buffer (buf b = sT + b*4096
    // elems, 8KB each); sT proper is first written only after layer 1 ends.
    __shared__ __align__(16) short sT[128 * 128];
    __shared__ int s_dst[128];
    __shared__ float s_dist[128], s_dir[384], sGate[128];

    const int tid = threadIdx.x;
    const int lane = tid & 63;
    const int w = tid >> 6;
    const int lc = lane & 15;
    const int quad = lane >> 4;
    const int e0 = blockIdx.x * 128;

    // per-lane staging descriptors: 4 lanes per row, 16B per lane
    const int part = lane & 3;
    const int r0 = w * 32 + (lane >> 2);    // rows w*32 .. w*32+15
    const int r1 = r0 + 16;                 // rows w*32+16 .. w*32+31
    const int es0 = ei[e0 + r0], ed0 = ei[N_EDGES + e0 + r0];
    const int es1 = ei[e0 + r1], ed1 = ei[N_EDGES + e0 + r1];

    // stage chunk kc (<8) into buf: async gather, contiguous 1KB per issue
#define STAGE_H(kc_, buf_) do {                                              \
        const int ss = ((kc_) < 4);                                          \
        const int ko = ((kc_) & 3) * 32 + part * 8;                          \
        gl_lds16(h_bf + (size_t)(ss ? es0 : ed0) * 128 + ko,                 \
                 &sT[(buf_) * 4096 + w * 1024]);                             \
        gl_lds16(h_bf + (size_t)(ss ? es1 : ed1) * 128 + ko,                 \
                 &sT[(buf_) * 4096 + w * 1024 + 512]);                       \
    } while (0)

    // issue chunk 0 before the preamble
    STAGE_H(0, 0);

    // preamble: dist / unit dir / dst / gate-accum init
    if (tid < 128) {
        int e = e0 + tid;
        int s = ei[e], d = ei[N_EDGES + e];
        s_dst[tid] = d;
        float ddx = x[d * 3 + 0] - x[s * 3 + 0];
        float ddy = x[d * 3 + 1] - x[s * 3 + 1];
        float ddz = x[d * 3 + 2] - x[s * 3 + 2];
        float dot = ddx * ddx + ddy * ddy + ddz * ddz;
        s_dist[tid] = sqrtf(dot + 1e-9f);
        float inv = 1.0f / (sqrtf(dot) + 1e-9f);
        s_dir[tid * 3 + 0] = ddx * inv;
        s_dir[tid * 3 + 1] = ddy * inv;
        s_dir[tid * 3 + 2] = ddz * inv;
        sGate[tid] = 0.0f;
    }

    const int ct0 = 2 * w, ct1 = 2 * w + 1;
    const int c0 = ct0 * 16 + lc, c1 = c0 + 16;

    floatx4 acc[8][2];
#pragma unroll
    for (int rt = 0; rt < 8; ++rt)
#pragma unroll
        for (int ct = 0; ct < 2; ++ct)
#pragma unroll
            for (int r = 0; r < 4; ++r) acc[rt][ct][r] = 0.0f;

    // ---- phi_e layer 1: K = 288 (h_src | h_dst | ea | dist | pad) ----
    // single barrier per chunk: stage kc+1 after the barrier, compute kc.
    for (int kc = 0; kc < 9; ++kc) {
        __syncthreads();
        if (kc < 7) {
            STAGE_H(kc + 1, (kc + 1) & 1);
        } else if (kc == 7) {
            // stage ea+dist chunk (k 256..287) into buf0, plain writes
            if (tid < 128) {
                const float4* p = (const float4*)&ea[(size_t)(e0 + tid) * 16];
                float4 a = p[0], b = p[1], c = p[2], d = p[3];
                uint4* dst = (uint4*)&sT[0 * 4096 + tid * 32];
                dst[0] = make_uint4(f2bf_u(a.x) | (f2bf_u(a.y) << 16),
                                    f2bf_u(a.z) | (f2bf_u(a.w) << 16),
                                    f2bf_u(b.x) | (f2bf_u(b.y) << 16),
                                    f2bf_u(b.z) | (f2bf_u(b.w) << 16));
                dst[1] = make_uint4(f2bf_u(c.x) | (f2bf_u(c.y) << 16),
                                    f2bf_u(c.z) | (f2bf_u(c.w) << 16),
                                    f2bf_u(d.x) | (f2bf_u(d.y) << 16),
                                    f2bf_u(d.z) | (f2bf_u(d.w) << 16));
                dst[2] = make_uint4(f2bf_u(s_dist[tid]), 0u, 0u, 0u);
                dst[3] = make_uint4(0u, 0u, 0u, 0u);
            }
        }
        const int buf = kc & 1;
        bf16x8 b0 = *(const bf16x8*)&pWe1[((size_t)(kc * 8 + ct0) * 64 + lane) * 8];
        bf16x8 b1 = *(const bf16x8*)&pWe1[((size_t)(kc * 8 + ct1) * 64 + lane) * 8];
#pragma unroll
        for (int rt = 0; rt < 8; ++rt) {
            bf16x8 a = *(const bf16x8*)&sT[buf * 4096 + (rt * 16 + lc) * 32 + quad * 8];
            acc[rt][0] = __builtin_amdgcn_mfma_f32_16x16x32_bf16(a, b0, acc[rt][0], 0, 0, 0);
            acc[rt][1] = __builtin_amdgcn_mfma_f32_16x16x32_bf16(a, b1, acc[rt][1], 0, 0, 0);
        }
    }
    __syncthreads();   // all layer-1 reads done; sT region now free

    // epilogue 1: bias + silu -> sT (bf16, swizzled)
    {
        float bb0 = be1[c0], bb1 = be1[c1];
#pragma unroll
        for (int rt = 0; rt < 8; ++rt)
#pragma unroll
            for (int r = 0; r < 4; ++r) {
                int row = rt * 16 + quad * 4 + r;
                sT[sT_idx(row, c0)] = f2bf(silu_f(acc[rt][0][r] + bb0));
                sT[sT_idx(row, c1)] = f2bf(silu_f(acc[rt][1][r] + bb1));
            }
    }
    __syncthreads();

    // ---- phi_e layer 2: m = t1 @ We2 + be2 ----
#pragma unroll
    for (int rt = 0; rt < 8; ++rt)
#pragma unroll
        for (int ct = 0; ct < 2; ++ct)
#pragma unroll
            for (int r = 0; r < 4; ++r) acc[rt][ct][r] = 0.0f;

    for (int kc = 0; kc < 4; ++kc) {
        bf16x8 b0 = *(const bf16x8*)&pWe2[((size_t)(kc * 8 + ct0) * 64 + lane) * 8];
        bf16x8 b1 = *(const bf16x8*)&pWe2[((size_t)(kc * 8 + ct1) * 64 + lane) * 8];
#pragma unroll
        for (int rt = 0; rt < 8; ++rt) {
            int kb = (kc * 4 + quad) ^ ((lc >> 1) & 7);
            bf16x8 a = *(const bf16x8*)&sT[(rt * 16 + lc) * 128 + kb * 8];
            acc[rt][0] = __builtin_amdgcn_mfma_f32_16x16x32_bf16(a, b0, acc[rt][0], 0, 0, 0);
            acc[rt][1] = __builtin_amdgcn_mfma_f32_16x16x32_bf16(a, b1, acc[rt][1], 0, 0, 0);
        }
    }
    {
        float bb0 = be2[c0], bb1 = be2[c1];
#pragma unroll
        for (int rt = 0; rt < 8; ++rt)
#pragma unroll
            for (int r = 0; r < 4; ++r) {
                acc[rt][0][r] += bb0;
                acc[rt][1][r] += bb1;
            }
    }
    __syncthreads();   // all waves done reading t1 from sT

    // scatter m -> agg (fp32 atomics) and write m -> sT for phi_x
#pragma unroll
    for (int rt = 0; rt < 8; ++rt)
#pragma unroll
        for (int r = 0; r < 4; ++r) {
            int row = rt * 16 + quad * 4 + r;
            int d = s_dst[row];
            atomicAdd(&agg[(size_t)d * HDIM + c0], acc[rt][0][r]);
            atomicAdd(&agg[(size_t)d * HDIM + c1], acc[rt][1][r]);
            sT[sT_idx(row, c0)] = f2bf(acc[rt][0][r]);
            sT[sT_idx(row, c1)] = f2bf(acc[rt][1][r]);
        }
    __syncthreads();

    // ---- phi_x: u = silu(m @ Wx1 + bx1); gate = u . Wx2 + bx2 ----
#pragma unroll
    for (int rt = 0; rt < 8; ++rt)
#pragma unroll
        for (int ct = 0; ct < 2; ++ct)
#pragma unroll
            for (int r = 0; r < 4; ++r) acc[rt][ct][r] = 0.0f;

    for (int kc = 0; kc < 4; ++kc) {
        bf16x8 b0 = *(const bf16x8*)&pWx1[((size_t)(kc * 8 + ct0) * 64 + lane) * 8];
        bf16x8 b1 = *(const bf16x8*)&pWx1[((size_t)(kc * 8 + ct1) * 64 + lane) * 8];
#pragma unroll
        for (int rt = 0; rt < 8; ++rt) {
            int kb = (kc * 4 + quad) ^ ((lc >> 1) & 7);
            bf16x8 a = *(const bf16x8*)&sT[(rt * 16 + lc) * 128 + kb * 8];
            acc[rt][0] = __builtin_amdgcn_mfma_f32_16x16x32_bf16(a, b0, acc[rt][0], 0, 0, 0);
            acc[rt][1] = __builtin_amdgcn_mfma_f32_16x16x32_bf16(a, b1, acc[rt][1], 0, 0, 0);
        }
    }
    {
        float wx0 = Wx2[c0], wx1 = Wx2[c1];
        float bb0 = bx1[c0], bb1 = bx1[c1];
        float gp[8][4];
#pragma unroll
        for (int rt = 0; rt < 8; ++rt)
#pragma unroll
            for (int r = 0; r < 4; ++r)
                gp[rt][r] = silu_f(acc[rt][0][r] + bb0) * wx0 +
                            silu_f(acc[rt][1][r] + bb1) * wx1;
#pragma unroll
        for (int m = 1; m < 16; m <<= 1)
#pragma unroll
            for (int rt = 0; rt < 8; ++rt)
#pragma unroll
                for (int r = 0; r < 4; ++r)
                    gp[rt][r] += __shfl_xor(gp[rt][r], m, 64);
        if (lc == 0) {
#pragma unroll
            for (int rt = 0; rt < 8; ++rt)
#pragma unroll
                for (int r = 0; r < 4; ++r)
                    atomicAdd(&sGate[rt * 16 + quad * 4 + r], gp[rt][r]);
        }
    }
    __syncthreads();

    if (tid < 128) {
        float g = sGate[tid] + bx2[0];
        int d = s_dst[tid];
        atomicAdd(&dxb[(size_t)d * 3 + 0], s_dir[tid * 3 + 0] * g);
        atomicAdd(&dxb[(size_t)d * 3 + 1], s_dir[tid * 3 + 1] * g);
        atomicAdd(&dxb[(size_t)d * 3 + 2], s_dir[tid * 3 + 2] * g);
    }
#undef STAGE_H
}

__global__ __launch_bounds__(256, 4)
void egnn_node_mfma(const short* __restrict__ h_bf, const float* __restrict__ h,
                    const float* __restrict__ x,
                    const float* __restrict__ agg, const float* __restrict__ dxb,
                    const short* __restrict__ pWh1, const short* __restrict__ pWh2,
                    const float* __restrict__ bh1, const float* __restrict__ bh2,
                    const float* __restrict__ ln_g, const float* __restrict__ ln_b,
                    float* __restrict__ hout, float* __restrict__ xout) {
    __shared__ __align__(16) short sT[128 * 128];
    __shared__ float sS1[128], sS2[128];

    const int tid = threadIdx.x;
    const int lane = tid & 63;
    const int w = tid >> 6;
    const int lc = lane & 15;
    const int quad = lane >> 4;
    const int n0 = blockIdx.x * 128;

    const int part = lane & 3;
    const int r0 = w * 32 + (lane >> 2);
    const int r1 = r0 + 16;
    const int nr0 = (n0 + r0 < N_NODES) ? n0 + r0 : N_NODES - 1;
    const int nr1 = (n0 + r1 < N_NODES) ? n0 + r1 : N_NODES - 1;
    const int srow = tid >> 1;
    const int hf = tid & 1;
    const int nsrow = (n0 + srow < N_NODES) ? n0 + srow : N_NODES - 1;

    // stage chunk kc: kc<4 async from h_bf, kc>=4 convert from fp32 agg
#define STAGE_N(kc_, buf_) do {                                              \
        if ((kc_) < 4) {                                                     \
            const int ko = (kc_) * 32 + part * 8;                            \
            gl_lds16(h_bf + (size_t)nr0 * 128 + ko,                         \
                     &sT[(buf_) * 4096 + w * 1024]);                        \
            gl_lds16(h_bf + (size_t)nr1 * 128 + ko,                        \
                     &sT[(buf_) * 4096 + w * 1024 + 512]);                  \
        } else {                                                             \
            const float4* p = (const float4*)&agg[(size_t)nsrow * HDIM +     \
                                                  ((kc_) & 3) * 32 + hf * 16]; \
            float4 a = p[0], b = p[1], c = p[2], d = p[3];                   \
            uint4* dst2 = (uint4*)&sT[(buf_) * 4096 + srow * 32 + hf * 16];  \
            dst2[0] = make_uint4(f2bf_u(a.x) | (f2bf_u(a.y) << 16),          \
                                 f2bf_u(a.z) | (f2bf_u(a.w) << 16),          \
                                 f2bf_u(b.x) | (f2bf_u(b.y) << 16),          \
                                 f2bf_u(b.z) | (f2bf_u(b.w) << 16));         \
            dst2[1] = make_uint4(f2bf_u(c.x) | (f2bf_u(c.y) << 16),          \
                                 f2bf_u(c.z) | (f2bf_u(c.w) << 16),          \
                                 f2bf_u(d.x) | (f2bf_u(d.y) << 16),          \
                                 f2bf_u(d.z) | (f2bf_u(d.w) << 16));         \
        }                                                                    \
    } while (0)

    STAGE_N(0, 0);
    if (tid < 128) { sS1[tid] = 0.0f; sS2[tid] = 0.0f; }

    const int ct0 = 2 * w, ct1 = 2 * w + 1;
    const int c0 = ct0 * 16 + lc, c1 = c0 + 16;

    floatx4 acc[8][2];
#pragma unroll
    for (int rt = 0; rt < 8; ++rt)
#pragma unroll
        for (int ct = 0; ct < 2; ++ct)
#pragma unroll
            for (int r = 0; r < 4; ++r) acc[rt][ct][r] = 0.0f;

    // ---- phi_h layer 1: [h | agg] (K=256) ----
    for (int kc = 0; kc < 8; ++kc) {
        __syncthreads();
        if (kc < 7) STAGE_N(kc + 1, (kc + 1) & 1);
        const int buf = kc & 1;
        bf16x8 b0 = *(const bf16x8*)&pWh1[((size_t)(kc * 8 + ct0) * 64 + lane) * 8];
        bf16x8 b1 = *(const bf16x8*)&pWh1[((size_t)(kc * 8 + ct1) * 64 + lane) * 8];
#pragma unroll
        for (int rt = 0; rt < 8; ++rt) {
            bf16x8 a = *(const bf16x8*)&sT[buf * 4096 + (rt * 16 + lc) * 32 + quad * 8];
            acc[rt][0] = __builtin_amdgcn_mfma_f32_16x16x32_bf16(a, b0, acc[rt][0], 0, 0, 0);
            acc[rt][1] = __builtin_amdgcn_mfma_f32_16x16x32_bf16(a, b1, acc[rt][1], 0, 0, 0);
        }
    }
    __syncthreads();

    {
        float bb0 = bh1[c0], bb1 = bh1[c1];
#pragma unroll
        for (int rt = 0; rt < 8; ++rt)
#pragma unroll
            for (int r = 0; r < 4; ++r) {
                int row = rt * 16 + quad * 4 + r;
                sT[sT_idx(row, c0)] = f2bf(silu_f(acc[rt][0][r] + bb0));
                sT[sT_idx(row, c1)] = f2bf(silu_f(acc[rt][1][r] + bb1));
            }
    }
    __syncthreads();

    // ---- phi_h layer 2 ----
#pragma unroll
    for (int rt = 0; rt < 8; ++rt)
#pragma unroll
        for (int ct = 0; ct < 2; ++ct)
#pragma unroll
            for (int r = 0; r < 4; ++r) acc[rt][ct][r] = 0.0f;

    for (int kc = 0; kc < 4; ++kc) {
        bf16x8 b0 = *(const bf16x8*)&pWh2[((size_t)(kc * 8 + ct0) * 64 + lane) * 8];
        bf16x8 b1 = *(const bf16x8*)&pWh2[((size_t)(kc * 8 + ct1) * 64 + lane) * 8];
#pragma unroll
        for (int rt = 0; rt < 8; ++rt) {
            int kb = (kc * 4 + quad) ^ ((lc >> 1) & 7);
            bf16x8 a = *(const bf16x8*)&sT[(rt * 16 + lc) * 128 + kb * 8];
            acc[rt][0] = __builtin_amdgcn_mfma_f32_16x16x32_bf16(a, b0, acc[rt][0], 0, 0, 0);
            acc[rt][1] = __builtin_amdgcn_mfma_f32_16x16x32_bf16(a, b1, acc[rt][1], 0, 0, 0);
        }
    }

    // ---- residual + LayerNorm ----
    {
        float bb0 = bh2[c0], bb1 = bh2[c1];
#pragma unroll
        for (int rt = 0; rt < 8; ++rt)
#pragma unroll
            for (int r = 0; r < 4; ++r) {
                int row = rt * 16 + quad * 4 + r;
                int n = n0 + row;
                int nc = (n < N_NODES) ? n : (N_NODES - 1);
                float v0 = acc[rt][0][r] + bb0 + h[(size_t)nc * HDIM + c0];
                float v1 = acc[rt][1][r] + bb1 + h[(size_t)nc * HDIM + c1];
                acc[rt][0][r] = v0;
                acc[rt][1][r] = v1;
                float s1 = v0 + v1;
                float s2 = v0 * v0 + v1 * v1;
#pragma unroll
                for (int m = 1; m < 16; m <<= 1) {
                    s1 += __shfl_xor(s1, m, 64);
                    s2 += __shfl_xor(s2, m, 64);
                }
                if (lc == 0) {
                    atomicAdd(&sS1[row], s1);
                    atomicAdd(&sS2[row], s2);
                }
            }
    }
    __syncthreads();
    {
        float g0 = ln_g[c0], g1 = ln_g[c1];
        float lb0 = ln_b[c0], lb1 = ln_b[c1];
#pragma unroll
        for (int rt = 0; rt < 8; ++rt)
#pragma unroll
            for (int r = 0; r < 4; ++r) {
                int row = rt * 16 + quad * 4 + r;
                int n = n0 + row;
                if (n < N_NODES) {
                    float mu = sS1[row] * (1.0f / 128.0f);
                    float var = sS2[row] * (1.0f / 128.0f) - mu * mu;
                    float rs = rsqrtf(var + 1e-5f);
                    hout[(size_t)n * HDIM + c0] = (acc[rt][0][r] - mu) * rs * g0 + lb0;
                    hout[(size_t)n * HDIM + c1] = (acc[rt][1][r] - mu) * rs * g1 + lb1;
                }
            }
    }

    // ---- x_out = x + dx ----
    for (int f = tid; f < 384; f += 256) {
        int n = n0 + f / 3;
        int d = f - (f / 3) * 3;
        if (n < N_NODES) xout[(size_t)n * 3 + d] = x[(size_t)n * 3 + d] + dxb[(size_t)n * 3 + d];
    }
#undef STAGE_N
}

extern "C" void kernel_launch(void* const* d_in, const int* in_sizes, int n_in,
                              void* d_out, int out_size, void* d_ws, size_t ws_size,
                              hipStream_t stream) {
    (void)in_sizes; (void)n_in; (void)out_size;

    const float* h   = (const float*)d_in[0];
    const float* x   = (const float*)d_in[1];
    const int*   ei  = (const int*)d_in[2];
    const float* ea  = (const float*)d_in[3];
    const float* We1 = (const float*)d_in[4];
    const float* be1 = (const float*)d_in[5];
    const float* We2 = (const float*)d_in[6];
    const float* be2 = (const float*)d_in[7];
    const float* Wh1 = (const float*)d_in[8];
    const float* bh1 = (const float*)d_in[9];
    const float* Wh2 = (const float*)d_in[10];
    const float* bh2 = (const float*)d_in[11];
    const float* Wx1 = (const float*)d_in[12];
    const float* bx1 = (const float*)d_in[13];
    const float* Wx2 = (const float*)d_in[14];
    const float* bx2 = (const float*)d_in[15];
    const float* lng = (const float*)d_in[16];
    const float* lnb = (const float*)d_in[17];

    float* hout = (float*)d_out;
    float* xout = hout + (size_t)N_NODES * HDIM;

    const size_t CH = 8 * 64 * 8;   // 4096 bf16 per packed k-chunk
    const size_t oWe1 = 0, oWe2 = 9 * CH, oWx1 = 13 * CH, oWh1 = 17 * CH, oWh2 = 25 * CH;
    const size_t pwElems = 29 * CH;

    const size_t aggElems = (size_t)N_NODES * HDIM;
    const size_t dxbElems = (size_t)N_NODES * 3;
    const size_t aggB = aggElems * 4, dxbB = dxbElems * 4;
    const size_t pwB = pwElems * 2;
    const size_t hbB = (size_t)N_NODES * HDIM * 2;

    float* agg; float* dxb; short* pw; short* h_bf;
    char* ws = (char*)d_ws;
    if (ws_size >= aggB + dxbB + pwB + hbB) {
        agg  = (float*)ws;
        dxb  = (float*)(ws + aggB);
        pw   = (short*)(ws + aggB + dxbB);
        h_bf = (short*)(ws + aggB + dxbB + pwB);
    } else {
        // weights + h_bf in ws; agg/dxb alias d_out (node blocks read their
        // agg/dxb rows before overwriting them with hout/xout)
        pw   = (short*)ws;
        h_bf = (short*)(ws + pwB);
        agg  = (float*)d_out;
        dxb  = agg + aggElems;
    }

    hipMemsetAsync(agg, 0, aggB, stream);
    hipMemsetAsync(dxb, 0, dxbB, stream);

    pack_bf16_kernel<<<(N_NODES * HDIM / 8 + 255) / 256, 256, 0, stream>>>(h, h_bf,
                                                                           N_NODES * HDIM / 8);
    pack_w_kernel<<<(9 * 512 + 255) / 256, 256, 0, stream>>>(We1, pw + oWe1, 273, 9 * 512);
    pack_w_kernel<<<(4 * 512 + 255) / 256, 256, 0, stream>>>(We2, pw + oWe2, 128, 4 * 512);
    pack_w_kernel<<<(4 * 512 + 255) / 256, 256, 0, stream>>>(Wx1, pw + oWx1, 128, 4 * 512);
    pack_w_kernel<<<(8 * 512 + 255) / 256, 256, 0, stream>>>(Wh1, pw + oWh1, 256, 8 * 512);
    pack_w_kernel<<<(4 * 512 + 255) / 256, 256, 0, stream>>>(Wh2, pw + oWh2, 128, 4 * 512);

    egnn_edge_mfma<<<N_EDGES / 128, 256, 0, stream>>>(
        h_bf, x, ei, ea, pw + oWe1, pw + oWe2, pw + oWx1,
        be1, be2, bx1, Wx2, bx2, agg, dxb);

    egnn_node_mfma<<<(N_NODES + 127) / 128, 256, 0, stream>>>(
        h_bf, h, x, agg, dxb, pw + oWh1, pw + oWh2,
        bh1, bh2, lng, lnb, hout, xout);
}

// Round 4
// 629.391 us; speedup vs baseline: 1.2212x; 1.2212x over previous
//
#include <hip/hip_runtime.h>
#include <math.h>

#define N_NODES 50000
#define N_EDGES 800000
#define HDIM 128

typedef __attribute__((ext_vector_type(8))) short bf16x8;
typedef __attribute__((ext_vector_type(4))) float floatx4;

__device__ __forceinline__ unsigned f2bf_u(float f) {
    union { float f; unsigned u; } x; x.f = f;
    return (x.u + 0x7FFFu + ((x.u >> 16) & 1u)) >> 16;
}
__device__ __forceinline__ short f2bf(float f) { return (short)f2bf_u(f); }
__device__ __forceinline__ float bf2f(short s) {
    union { float f; unsigned u; } x; x.u = ((unsigned)(unsigned short)s) << 16;
    return x.f;
}
__device__ __forceinline__ float silu_f(float v) { return v / (1.0f + __expf(-v)); }

// async 16B/lane global->LDS DMA; lds base wave-uniform, HW adds lane*16.
__device__ __forceinline__ void gl_lds16(const void* g, void* l) {
    __builtin_amdgcn_global_load_lds(
        (const __attribute__((address_space(1))) unsigned int*)g,
        (__attribute__((address_space(3))) unsigned int*)l, 16, 0, 0);
}

// Swizzled LDS index for the 128-col bf16 activation buffer (C-write + A-read
// + column-walk all conflict-free; verified rounds 2-3).
__device__ __forceinline__ int sT_idx(int row, int c) {
    int kb = (c >> 3) ^ ((row >> 1) & 7);
    return row * 128 + kb * 8 + (c & 7);
}

// ---- weight packing: W (K x 128 fp32, k-major) -> bf16 MFMA B-frag order ----
__global__ void pack_w_kernel(const float* __restrict__ W, short* __restrict__ dst,
                              int K, int total) {
    int t = blockIdx.x * 256 + threadIdx.x;
    if (t >= total) return;
    int lane = t & 63;
    int ctk = t >> 6;
    int ct = ctk & 7, kc = ctk >> 3;
    int c = ct * 16 + (lane & 15);
    int kb = kc * 32 + (lane >> 4) * 8;
    bf16x8 v;
#pragma unroll
    for (int j = 0; j < 8; ++j) {
        int k = kb + j;
        v[j] = (k < K) ? f2bf(W[(size_t)k * HDIM + c]) : (short)0;
    }
    *(bf16x8*)&dst[(size_t)t * 8] = v;
}

// ---- fp32 -> bf16 row-major pack (h) ----
__global__ void pack_bf16_kernel(const float* __restrict__ src, short* __restrict__ dst,
                                 int n8) {
    int t = blockIdx.x * 256 + threadIdx.x;
    if (t >= n8) return;
    const float4* p = (const float4*)(src + (size_t)t * 8);
    float4 a = p[0], b = p[1];
    uint4 o;
    o.x = f2bf_u(a.x) | (f2bf_u(a.y) << 16);
    o.y = f2bf_u(a.z) | (f2bf_u(a.w) << 16);
    o.z = f2bf_u(b.x) | (f2bf_u(b.y) << 16);
    o.w = f2bf_u(b.z) | (f2bf_u(b.w) << 16);
    *(uint4*)(dst + (size_t)t * 8) = o;
}

// ---- CSR-lite build: histogram -> single-block scan -> scatter ----
__global__ void hist_kernel(const int* __restrict__ ei, int* __restrict__ cnt) {
    int e = blockIdx.x * 256 + threadIdx.x;
    if (e < N_EDGES) atomicAdd(&cnt[ei[N_EDGES + e]], 1);
}

__global__ __launch_bounds__(1024)
void scan_kernel(const int* __restrict__ cnt, int* __restrict__ cursor, int n) {
    __shared__ int wsum[16];
    __shared__ int s_carry;
    const int tid = threadIdx.x;
    const int lane = tid & 63, wid = tid >> 6;
    if (tid == 0) s_carry = 0;
    __syncthreads();
    for (int base = 0; base < n; base += 1024) {
        int i = base + tid;
        int v = (i < n) ? cnt[i] : 0;
        int s = v;
#pragma unroll
        for (int off = 1; off < 64; off <<= 1) {
            int t = __shfl_up(s, off, 64);
            if (lane >= off) s += t;
        }
        if (lane == 63) wsum[wid] = s;
        __syncthreads();
        if (wid == 0 && lane < 16) {
            int t = wsum[lane];
            int sc = t;
#pragma unroll
            for (int off = 1; off < 16; off <<= 1) {
                int tt = __shfl_up(sc, off, 64);
                if (lane >= off) sc += tt;
            }
            wsum[lane] = sc - t;   // exclusive
        }
        __syncthreads();
        int excl = s - v + wsum[wid] + s_carry;
        if (i < n) cursor[i] = excl;
        __syncthreads();
        if (tid == 1023) s_carry = excl + v;
        __syncthreads();
    }
}

__global__ void scatter_kernel(const int* __restrict__ ei, int* __restrict__ cursor,
                               int* __restrict__ eid) {
    int e = blockIdx.x * 256 + threadIdx.x;
    if (e >= N_EDGES) return;
    int d = ei[N_EDGES + e];
    int pos = atomicAdd(&cursor[d], 1);
    eid[pos] = e;
}

__global__ __launch_bounds__(256, 4)
void egnn_edge_mfma(const short* __restrict__ h_bf, const float* __restrict__ x,
                    const int* __restrict__ ei, const float* __restrict__ ea,
                    const int* __restrict__ eid_sorted,
                    const short* __restrict__ pWe1, const short* __restrict__ pWe2,
                    const short* __restrict__ pWx1,
                    const float* __restrict__ be1, const float* __restrict__ be2,
                    const float* __restrict__ bx1, const float* __restrict__ Wx2,
                    const float* __restrict__ bx2,
                    float* __restrict__ agg, float* __restrict__ dxb) {
    // sT doubles as the layer-1 staging double-buffer (buf b = sT + b*4096
    // elems, 8KB each); sT proper is first written only after layer 1 ends.
    __shared__ __align__(16) short sT[128 * 128];
    __shared__ int s_dst[128], s_eid[128];
    __shared__ float s_dist[128], s_dir[384], sGate[128];

    const int tid = threadIdx.x;
    const int lane = tid & 63;
    const int w = tid >> 6;
    const int lc = lane & 15;
    const int quad = lane >> 4;

    // XCD-locality swizzle: consecutive sorted ranges stay on one XCD so
    // atomic agg lines shared by adjacent blocks stay in one L2.
    int bix = blockIdx.x;
    int bid = (bix < 6248) ? (bix & 7) * 781 + (bix >> 3) : bix;
    const int e0 = bid * 128;

    // per-lane staging descriptors: 4 lanes per row, 16B per lane
    const int part = lane & 3;
    const int r0 = w * 32 + (lane >> 2);    // rows w*32 .. w*32+15
    const int r1 = r0 + 16;                 // rows w*32+16 .. w*32+31
    const int eS0 = eid_sorted[e0 + r0], eS1 = eid_sorted[e0 + r1];
    const int es0 = ei[eS0], ed0 = ei[N_EDGES + eS0];
    const int es1 = ei[eS1], ed1 = ei[N_EDGES + eS1];

#define STAGE_H(kc_, buf_) do {                                              \
        const int ss = ((kc_) < 4);                                          \
        const int ko = ((kc_) & 3) * 32 + part * 8;                          \
        gl_lds16(h_bf + (size_t)(ss ? es0 : ed0) * 128 + ko,                 \
                 &sT[(buf_) * 4096 + w * 1024]);                             \
        gl_lds16(h_bf + (size_t)(ss ? es1 : ed1) * 128 + ko,                 \
                 &sT[(buf_) * 4096 + w * 1024 + 512]);                       \
    } while (0)

    STAGE_H(0, 0);

    // preamble: per-edge dist / unit dir / dst
    if (tid < 128) {
        int e = eid_sorted[e0 + tid];
        s_eid[tid] = e;
        int s = ei[e], d = ei[N_EDGES + e];
        s_dst[tid] = d;
        float ddx = x[d * 3 + 0] - x[s * 3 + 0];
        float ddy = x[d * 3 + 1] - x[s * 3 + 1];
        float ddz = x[d * 3 + 2] - x[s * 3 + 2];
        float dot = ddx * ddx + ddy * ddy + ddz * ddz;
        s_dist[tid] = sqrtf(dot + 1e-9f);
        float inv = 1.0f / (sqrtf(dot) + 1e-9f);
        s_dir[tid * 3 + 0] = ddx * inv;
        s_dir[tid * 3 + 1] = ddy * inv;
        s_dir[tid * 3 + 2] = ddz * inv;
        sGate[tid] = 0.0f;
    }

    const int ct0 = 2 * w, ct1 = 2 * w + 1;
    const int c0 = ct0 * 16 + lc, c1 = c0 + 16;

    floatx4 acc[8][2];
#pragma unroll
    for (int rt = 0; rt < 8; ++rt)
#pragma unroll
        for (int ct = 0; ct < 2; ++ct)
#pragma unroll
            for (int r = 0; r < 4; ++r) acc[rt][ct][r] = 0.0f;

    // ---- phi_e layer 1: K = 288 (h_src | h_dst | ea | dist | pad) ----
    for (int kc = 0; kc < 9; ++kc) {
        __syncthreads();
        if (kc < 7) {
            STAGE_H(kc + 1, (kc + 1) & 1);
        } else if (kc == 7) {
            if (tid < 128) {
                const float4* p = (const float4*)&ea[(size_t)s_eid[tid] * 16];
                float4 a = p[0], b = p[1], c = p[2], d = p[3];
                uint4* dst = (uint4*)&sT[0 * 4096 + tid * 32];
                dst[0] = make_uint4(f2bf_u(a.x) | (f2bf_u(a.y) << 16),
                                    f2bf_u(a.z) | (f2bf_u(a.w) << 16),
                                    f2bf_u(b.x) | (f2bf_u(b.y) << 16),
                                    f2bf_u(b.z) | (f2bf_u(b.w) << 16));
                dst[1] = make_uint4(f2bf_u(c.x) | (f2bf_u(c.y) << 16),
                                    f2bf_u(c.z) | (f2bf_u(c.w) << 16),
                                    f2bf_u(d.x) | (f2bf_u(d.y) << 16),
                                    f2bf_u(d.z) | (f2bf_u(d.w) << 16));
                dst[2] = make_uint4(f2bf_u(s_dist[tid]), 0u, 0u, 0u);
                dst[3] = make_uint4(0u, 0u, 0u, 0u);
            }
        }
        const int buf = kc & 1;
        bf16x8 b0 = *(const bf16x8*)&pWe1[((size_t)(kc * 8 + ct0) * 64 + lane) * 8];
        bf16x8 b1 = *(const bf16x8*)&pWe1[((size_t)(kc * 8 + ct1) * 64 + lane) * 8];
#pragma unroll
        for (int rt = 0; rt < 8; ++rt) {
            bf16x8 a = *(const bf16x8*)&sT[buf * 4096 + (rt * 16 + lc) * 32 + quad * 8];
            acc[rt][0] = __builtin_amdgcn_mfma_f32_16x16x32_bf16(a, b0, acc[rt][0], 0, 0, 0);
            acc[rt][1] = __builtin_amdgcn_mfma_f32_16x16x32_bf16(a, b1, acc[rt][1], 0, 0, 0);
        }
    }
    __syncthreads();

    // epilogue 1: bias + silu -> sT (bf16, swizzled)
    {
        float bb0 = be1[c0], bb1 = be1[c1];
#pragma unroll
        for (int rt = 0; rt < 8; ++rt)
#pragma unroll
            for (int r = 0; r < 4; ++r) {
                int row = rt * 16 + quad * 4 + r;
                sT[sT_idx(row, c0)] = f2bf(silu_f(acc[rt][0][r] + bb0));
                sT[sT_idx(row, c1)] = f2bf(silu_f(acc[rt][1][r] + bb1));
            }
    }
    __syncthreads();

    // ---- phi_e layer 2: m = t1 @ We2 + be2 ----
#pragma unroll
    for (int rt = 0; rt < 8; ++rt)
#pragma unroll
        for (int ct = 0; ct < 2; ++ct)
#pragma unroll
            for (int r = 0; r < 4; ++r) acc[rt][ct][r] = 0.0f;

    for (int kc = 0; kc < 4; ++kc) {
        bf16x8 b0 = *(const bf16x8*)&pWe2[((size_t)(kc * 8 + ct0) * 64 + lane) * 8];
        bf16x8 b1 = *(const bf16x8*)&pWe2[((size_t)(kc * 8 + ct1) * 64 + lane) * 8];
#pragma unroll
        for (int rt = 0; rt < 8; ++rt) {
            int kb = (kc * 4 + quad) ^ ((lc >> 1) & 7);
            bf16x8 a = *(const bf16x8*)&sT[(rt * 16 + lc) * 128 + kb * 8];
            acc[rt][0] = __builtin_amdgcn_mfma_f32_16x16x32_bf16(a, b0, acc[rt][0], 0, 0, 0);
            acc[rt][1] = __builtin_amdgcn_mfma_f32_16x16x32_bf16(a, b1, acc[rt][1], 0, 0, 0);
        }
    }
    {
        float bb0 = be2[c0], bb1 = be2[c1];
#pragma unroll
        for (int rt = 0; rt < 8; ++rt)
#pragma unroll
            for (int r = 0; r < 4; ++r) {
                acc[rt][0][r] += bb0;
                acc[rt][1][r] += bb1;
            }
    }
    __syncthreads();   // all waves done reading t1 from sT

    // write m -> sT (bf16, swizzled) for phi_x and for the agg column-walk
#pragma unroll
    for (int rt = 0; rt < 8; ++rt)
#pragma unroll
        for (int r = 0; r < 4; ++r) {
            int row = rt * 16 + quad * 4 + r;
            sT[sT_idx(row, c0)] = f2bf(acc[rt][0][r]);
            sT[sT_idx(row, c1)] = f2bf(acc[rt][1][r]);
        }
    __syncthreads();

    // ---- phi_x: u = silu(m @ Wx1 + bx1); gate = u . Wx2 + bx2 ----
#pragma unroll
    for (int rt = 0; rt < 8; ++rt)
#pragma unroll
        for (int ct = 0; ct < 2; ++ct)
#pragma unroll
            for (int r = 0; r < 4; ++r) acc[rt][ct][r] = 0.0f;

    for (int kc = 0; kc < 4; ++kc) {
        bf16x8 b0 = *(const bf16x8*)&pWx1[((size_t)(kc * 8 + ct0) * 64 + lane) * 8];
        bf16x8 b1 = *(const bf16x8*)&pWx1[((size_t)(kc * 8 + ct1) * 64 + lane) * 8];
#pragma unroll
        for (int rt = 0; rt < 8; ++rt) {
            int kb = (kc * 4 + quad) ^ ((lc >> 1) & 7);
            bf16x8 a = *(const bf16x8*)&sT[(rt * 16 + lc) * 128 + kb * 8];
            acc[rt][0] = __builtin_amdgcn_mfma_f32_16x16x32_bf16(a, b0, acc[rt][0], 0, 0, 0);
            acc[rt][1] = __builtin_amdgcn_mfma_f32_16x16x32_bf16(a, b1, acc[rt][1], 0, 0, 0);
        }
    }

    // ---- segmented agg scatter: column-walk over dst-sorted rows ----
    // dst uniform per row => wave-uniform branches; one coalesced 256B atomic
    // burst per (run, col-half). ~8 runs per block instead of 128.
    {
        const int c = tid & 127;
        const int rb = (tid >> 7) * 64;
        float run = 0.0f;
        int cur = s_dst[rb];
        for (int r = rb; r < rb + 64; ++r) {
            int d = s_dst[r];
            if (d != cur) {
                atomicAdd(&agg[(size_t)cur * HDIM + c], run);
                run = 0.0f; cur = d;
            }
            run += bf2f(sT[sT_idx(r, c)]);
        }
        atomicAdd(&agg[(size_t)cur * HDIM + c], run);
    }

    // gate epilogue
    {
        float wx0 = Wx2[c0], wx1 = Wx2[c1];
        float bb0 = bx1[c0], bb1 = bx1[c1];
        float gp[8][4];
#pragma unroll
        for (int rt = 0; rt < 8; ++rt)
#pragma unroll
            for (int r = 0; r < 4; ++r)
                gp[rt][r] = silu_f(acc[rt][0][r] + bb0) * wx0 +
                            silu_f(acc[rt][1][r] + bb1) * wx1;
#pragma unroll
        for (int m = 1; m < 16; m <<= 1)
#pragma unroll
            for (int rt = 0; rt < 8; ++rt)
#pragma unroll
                for (int r = 0; r < 4; ++r)
                    gp[rt][r] += __shfl_xor(gp[rt][r], m, 64);
        if (lc == 0) {
#pragma unroll
            for (int rt = 0; rt < 8; ++rt)
#pragma unroll
                for (int r = 0; r < 4; ++r)
                    atomicAdd(&sGate[rt * 16 + quad * 4 + r], gp[rt][r]);
        }
    }
    __syncthreads();

    // ---- segmented dx scatter (16 row-chunks x 3 comps) ----
    if (tid < 48) {
        const int comp = tid % 3;
        const int ch = tid / 3;
        const float b2 = bx2[0];
        int r = ch * 8;
        float run = 0.0f;
        int cur = s_dst[r];
        for (int k = 0; k < 8; ++k, ++r) {
            int d = s_dst[r];
            if (d != cur) {
                atomicAdd(&dxb[(size_t)cur * 3 + comp], run);
                run = 0.0f; cur = d;
            }
            run += s_dir[r * 3 + comp] * (sGate[r] + b2);
        }
        atomicAdd(&dxb[(size_t)cur * 3 + comp], run);
    }
#undef STAGE_H
}

__global__ __launch_bounds__(256, 4)
void egnn_node_mfma(const short* __restrict__ h_bf, const float* __restrict__ h,
                    const float* __restrict__ x,
                    const float* __restrict__ agg, const float* __restrict__ dxb,
                    const short* __restrict__ pWh1, const short* __restrict__ pWh2,
                    const float* __restrict__ bh1, const float* __restrict__ bh2,
                    const float* __restrict__ ln_g, const float* __restrict__ ln_b,
                    float* __restrict__ hout, float* __restrict__ xout) {
    // 64 nodes per block (782 blocks: avoids round-3's 391-block starvation)
    __shared__ __align__(16) short sT[64 * 128];
    __shared__ float sS1[64], sS2[64];

    const int tid = threadIdx.x;
    const int lane = tid & 63;
    const int w = tid >> 6;
    const int lc = lane & 15;
    const int quad = lane >> 4;
    const int n0 = blockIdx.x * 64;

#define STAGE_N(kc_, buf_) do {                                              \
        if ((kc_) < 4) {                                                     \
            const int ko = (kc_) * 32 + (lane & 3) * 8;                      \
            const int row = w * 16 + (lane >> 2);                            \
            const int n = (n0 + row < N_NODES) ? n0 + row : N_NODES - 1;     \
            gl_lds16(h_bf + (size_t)n * 128 + ko,                            \
                     &sT[(buf_) * 2048 + w * 512]);                          \
        } else {                                                             \
            const int srow = tid >> 2, prt = tid & 3;                        \
            const int n = (n0 + srow < N_NODES) ? n0 + srow : N_NODES - 1;   \
            const float4* p = (const float4*)&agg[(size_t)n * HDIM +         \
                                                  ((kc_) & 3) * 32 + prt * 8]; \
            float4 a = p[0], b = p[1];                                       \
            *(uint4*)&sT[(buf_) * 2048 + srow * 32 + prt * 8] =              \
                make_uint4(f2bf_u(a.x) | (f2bf_u(a.y) << 16),                \
                           f2bf_u(a.z) | (f2bf_u(a.w) << 16),                \
                           f2bf_u(b.x) | (f2bf_u(b.y) << 16),                \
                           f2bf_u(b.z) | (f2bf_u(b.w) << 16));               \
        }                                                                    \
    } while (0)

    STAGE_N(0, 0);
    if (tid < 64) { sS1[tid] = 0.0f; sS2[tid] = 0.0f; }

    const int ct0 = 2 * w, ct1 = 2 * w + 1;
    const int c0 = ct0 * 16 + lc, c1 = c0 + 16;

    floatx4 acc[4][2];
#pragma unroll
    for (int rt = 0; rt < 4; ++rt)
#pragma unroll
        for (int ct = 0; ct < 2; ++ct)
#pragma unroll
            for (int r = 0; r < 4; ++r) acc[rt][ct][r] = 0.0f;

    // ---- phi_h layer 1: [h | agg] (K=256) ----
    for (int kc = 0; kc < 8; ++kc) {
        __syncthreads();
        if (kc < 7) STAGE_N(kc + 1, (kc + 1) & 1);
        const int buf = kc & 1;
        bf16x8 b0 = *(const bf16x8*)&pWh1[((size_t)(kc * 8 + ct0) * 64 + lane) * 8];
        bf16x8 b1 = *(const bf16x8*)&pWh1[((size_t)(kc * 8 + ct1) * 64 + lane) * 8];
#pragma unroll
        for (int rt = 0; rt < 4; ++rt) {
            bf16x8 a = *(const bf16x8*)&sT[buf * 2048 + (rt * 16 + lc) * 32 + quad * 8];
            acc[rt][0] = __builtin_amdgcn_mfma_f32_16x16x32_bf16(a, b0, acc[rt][0], 0, 0, 0);
            acc[rt][1] = __builtin_amdgcn_mfma_f32_16x16x32_bf16(a, b1, acc[rt][1], 0, 0, 0);
        }
    }
    __syncthreads();

    {
        float bb0 = bh1[c0], bb1 = bh1[c1];
#pragma unroll
        for (int rt = 0; rt < 4; ++rt)
#pragma unroll
            for (int r = 0; r < 4; ++r) {
                int row = rt * 16 + quad * 4 + r;
                sT[sT_idx(row, c0)] = f2bf(silu_f(acc[rt][0][r] + bb0));
                sT[sT_idx(row, c1)] = f2bf(silu_f(acc[rt][1][r] + bb1));
            }
    }
    __syncthreads();

    // ---- phi_h layer 2 ----
#pragma unroll
    for (int rt = 0; rt < 4; ++rt)
#pragma unroll
        for (int ct = 0; ct < 2; ++ct)
#pragma unroll
            for (int r = 0; r < 4; ++r) acc[rt][ct][r] = 0.0f;

    for (int kc = 0; kc < 4; ++kc) {
        bf16x8 b0 = *(const bf16x8*)&pWh2[((size_t)(kc * 8 + ct0) * 64 + lane) * 8];
        bf16x8 b1 = *(const bf16x8*)&pWh2[((size_t)(kc * 8 + ct1) * 64 + lane) * 8];
#pragma unroll
        for (int rt = 0; rt < 4; ++rt) {
            int kb = (kc * 4 + quad) ^ ((lc >> 1) & 7);
            bf16x8 a = *(const bf16x8*)&sT[(rt * 16 + lc) * 128 + kb * 8];
            acc[rt][0] = __builtin_amdgcn_mfma_f32_16x16x32_bf16(a, b0, acc[rt][0], 0, 0, 0);
            acc[rt][1] = __builtin_amdgcn_mfma_f32_16x16x32_bf16(a, b1, acc[rt][1], 0, 0, 0);
        }
    }

    // ---- residual + LayerNorm ----
    {
        float bb0 = bh2[c0], bb1 = bh2[c1];
#pragma unroll
        for (int rt = 0; rt < 4; ++rt)
#pragma unroll
            for (int r = 0; r < 4; ++r) {
                int row = rt * 16 + quad * 4 + r;
                int n = n0 + row;
                int nc = (n < N_NODES) ? n : (N_NODES - 1);
                float v0 = acc[rt][0][r] + bb0 + h[(size_t)nc * HDIM + c0];
                float v1 = acc[rt][1][r] + bb1 + h[(size_t)nc * HDIM + c1];
                acc[rt][0][r] = v0;
                acc[rt][1][r] = v1;
                float s1 = v0 + v1;
                float s2 = v0 * v0 + v1 * v1;
#pragma unroll
                for (int m = 1; m < 16; m <<= 1) {
                    s1 += __shfl_xor(s1, m, 64);
                    s2 += __shfl_xor(s2, m, 64);
                }
                if (lc == 0) {
                    atomicAdd(&sS1[row], s1);
                    atomicAdd(&sS2[row], s2);
                }
            }
    }
    __syncthreads();
    {
        float g0 = ln_g[c0], g1 = ln_g[c1];
        float lb0 = ln_b[c0], lb1 = ln_b[c1];
#pragma unroll
        for (int rt = 0; rt < 4; ++rt)
#pragma unroll
            for (int r = 0; r < 4; ++r) {
                int row = rt * 16 + quad * 4 + r;
                int n = n0 + row;
                if (n < N_NODES) {
                    float mu = sS1[row] * (1.0f / 128.0f);
                    float var = sS2[row] * (1.0f / 128.0f) - mu * mu;
                    float rs = rsqrtf(var + 1e-5f);
                    hout[(size_t)n * HDIM + c0] = (acc[rt][0][r] - mu) * rs * g0 + lb0;
                    hout[(size_t)n * HDIM + c1] = (acc[rt][1][r] - mu) * rs * g1 + lb1;
                }
            }
    }

    // ---- x_out = x + dx ----
    if (tid < 192) {
        int n = n0 + tid / 3;
        int d = tid - (tid / 3) * 3;
        if (n < N_NODES) xout[(size_t)n * 3 + d] = x[(size_t)n * 3 + d] + dxb[(size_t)n * 3 + d];
    }
#undef STAGE_N
}

extern "C" void kernel_launch(void* const* d_in, const int* in_sizes, int n_in,
                              void* d_out, int out_size, void* d_ws, size_t ws_size,
                              hipStream_t stream) {
    (void)in_sizes; (void)n_in; (void)out_size;

    const float* h   = (const float*)d_in[0];
    const float* x   = (const float*)d_in[1];
    const int*   ei  = (const int*)d_in[2];
    const float* ea  = (const float*)d_in[3];
    const float* We1 = (const float*)d_in[4];
    const float* be1 = (const float*)d_in[5];
    const float* We2 = (const float*)d_in[6];
    const float* be2 = (const float*)d_in[7];
    const float* Wh1 = (const float*)d_in[8];
    const float* bh1 = (const float*)d_in[9];
    const float* Wh2 = (const float*)d_in[10];
    const float* bh2 = (const float*)d_in[11];
    const float* Wx1 = (const float*)d_in[12];
    const float* bx1 = (const float*)d_in[13];
    const float* Wx2 = (const float*)d_in[14];
    const float* bx2 = (const float*)d_in[15];
    const float* lng = (const float*)d_in[16];
    const float* lnb = (const float*)d_in[17];

    float* hout = (float*)d_out;
    float* xout = hout + (size_t)N_NODES * HDIM;

    const size_t CH = 8 * 64 * 8;   // 4096 bf16 per packed k-chunk
    const size_t oWe1 = 0, oWe2 = 9 * CH, oWx1 = 13 * CH, oWh1 = 17 * CH, oWh2 = 25 * CH;
    const size_t pwElems = 29 * CH;

    const size_t aggElems = (size_t)N_NODES * HDIM;
    const size_t dxbElems = (size_t)N_NODES * 3;
    const size_t aggB = aggElems * 4, dxbB = dxbElems * 4;
    const size_t pwB = pwElems * 2;
    const size_t hbB = (size_t)N_NODES * HDIM * 2;
    const size_t cntB = (size_t)N_NODES * 4;
    const size_t eidB = (size_t)N_EDGES * 4;

    char* ws = (char*)d_ws;
    float* agg; float* dxb; short* pw; short* h_bf; int* cnt; int* cursor; int* eid;
    if (ws_size >= aggB + dxbB + pwB + hbB + 2 * cntB + eidB) {
        agg    = (float*)ws;
        dxb    = (float*)(ws + aggB);
        pw     = (short*)(ws + aggB + dxbB);
        h_bf   = (short*)(ws + aggB + dxbB + pwB);
        cnt    = (int*)(ws + aggB + dxbB + pwB + hbB);
        cursor = (int*)(ws + aggB + dxbB + pwB + hbB + cntB);
        eid    = (int*)(ws + aggB + dxbB + pwB + hbB + 2 * cntB);
    } else {
        // fallback: agg/dxb alias d_out (node blocks read their agg/dxb rows
        // before overwriting with hout/xout)
        pw     = (short*)ws;
        h_bf   = (short*)(ws + pwB);
        cnt    = (int*)(ws + pwB + hbB);
        cursor = (int*)(ws + pwB + hbB + cntB);
        eid    = (int*)(ws + pwB + hbB + 2 * cntB);
        agg    = (float*)d_out;
        dxb    = agg + aggElems;
    }

    hipMemsetAsync(agg, 0, aggB, stream);
    hipMemsetAsync(dxb, 0, dxbB, stream);
    hipMemsetAsync(cnt, 0, cntB, stream);

    pack_bf16_kernel<<<(N_NODES * HDIM / 8 + 255) / 256, 256, 0, stream>>>(
        h, h_bf, N_NODES * HDIM / 8);
    pack_w_kernel<<<(9 * 512 + 255) / 256, 256, 0, stream>>>(We1, pw + oWe1, 273, 9 * 512);
    pack_w_kernel<<<(4 * 512 + 255) / 256, 256, 0, stream>>>(We2, pw + oWe2, 128, 4 * 512);
    pack_w_kernel<<<(4 * 512 + 255) / 256, 256, 0, stream>>>(Wx1, pw + oWx1, 128, 4 * 512);
    pack_w_kernel<<<(8 * 512 + 255) / 256, 256, 0, stream>>>(Wh1, pw + oWh1, 256, 8 * 512);
    pack_w_kernel<<<(4 * 512 + 255) / 256, 256, 0, stream>>>(Wh2, pw + oWh2, 128, 4 * 512);

    hist_kernel<<<(N_EDGES + 255) / 256, 256, 0, stream>>>(ei, cnt);
    scan_kernel<<<1, 1024, 0, stream>>>(cnt, cursor, N_NODES);
    scatter_kernel<<<(N_EDGES + 255) / 256, 256, 0, stream>>>(ei, cursor, eid);

    egnn_edge_mfma<<<N_EDGES / 128, 256, 0, stream>>>(
        h_bf, x, ei, ea, eid, pw + oWe1, pw + oWe2, pw + oWx1,
        be1, be2, bx1, Wx2, bx2, agg, dxb);

    egnn_node_mfma<<<(N_NODES + 63) / 64, 256, 0, stream>>>(
        h_bf, h, x, agg, dxb, pw + oWh1, pw + oWh2,
        bh1, bh2, lng, lnb, hout, xout);
}

// Round 5
// 587.678 us; speedup vs baseline: 1.3078x; 1.0710x over previous
//
#include <hip/hip_runtime.h>
#include <math.h>

#define N_NODES 50000
#define N_EDGES 800000
#define HDIM 128

typedef __attribute__((ext_vector_type(8))) short bf16x8;
typedef __attribute__((ext_vector_type(4))) float floatx4;

__device__ __forceinline__ unsigned f2bf_u(float f) {
    union { float f; unsigned u; } x; x.f = f;
    return (x.u + 0x7FFFu + ((x.u >> 16) & 1u)) >> 16;
}
__device__ __forceinline__ short f2bf(float f) { return (short)f2bf_u(f); }
__device__ __forceinline__ float bf2f(short s) {
    union { float f; unsigned u; } x; x.u = ((unsigned)(unsigned short)s) << 16;
    return x.f;
}
__device__ __forceinline__ float fast_rcp(float x) {
    float r; asm("v_rcp_f32 %0, %1" : "=v"(r) : "v"(x)); return r;
}
// silu without the fp32 division sequence (v_rcp: ~1ulp, fine for bf16 pipeline)
__device__ __forceinline__ float silu_f(float v) {
    return v * fast_rcp(1.0f + __expf(-v));
}

// async 16B/lane global->LDS DMA; lds base wave-uniform, HW adds lane*16.
__device__ __forceinline__ void gl_lds16(const void* g, void* l) {
    __builtin_amdgcn_global_load_lds(
        (const __attribute__((address_space(1))) unsigned int*)g,
        (__attribute__((address_space(3))) unsigned int*)l, 16, 0, 0);
}

// Swizzled LDS index for the 128-col bf16 activation buffer (verified r2-r4).
__device__ __forceinline__ int sT_idx(int row, int c) {
    int kb = (c >> 3) ^ ((row >> 1) & 7);
    return row * 128 + kb * 8 + (c & 7);
}

// ---- all 5 weights -> bf16 MFMA B-frag order, one launch ----
// global chunk u = t>>9: We1 [0,9) K=273 | We2 [9,13) | Wx1 [13,17) |
// Wh1 [17,25) K=256 | Wh2 [25,29). pw layout matches chunk order.
__global__ void pack_all_w(const float* __restrict__ We1, const float* __restrict__ We2,
                           const float* __restrict__ Wx1, const float* __restrict__ Wh1,
                           const float* __restrict__ Wh2, short* __restrict__ pw) {
    int t = blockIdx.x * 256 + threadIdx.x;
    if (t >= 29 * 512) return;
    int u = t >> 9;
    const float* W; int K, base;
    if (u < 9)       { W = We1; K = 273; base = 0; }
    else if (u < 13) { W = We2; K = 128; base = 9; }
    else if (u < 17) { W = Wx1; K = 128; base = 13; }
    else if (u < 25) { W = Wh1; K = 256; base = 17; }
    else             { W = Wh2; K = 128; base = 25; }
    int tl = t - base * 512;
    int lane = tl & 63;
    int ctk = tl >> 6;
    int ct = ctk & 7, kc = ctk >> 3;
    int c = ct * 16 + (lane & 15);
    int kb = kc * 32 + (lane >> 4) * 8;
    bf16x8 v;
#pragma unroll
    for (int j = 0; j < 8; ++j) {
        int k = kb + j;
        v[j] = (k < K) ? f2bf(W[(size_t)k * HDIM + c]) : (short)0;
    }
    *(bf16x8*)&pw[(size_t)t * 8] = v;
}

// ---- fp32 -> bf16 row-major pack (h) ----
__global__ void pack_bf16_kernel(const float* __restrict__ src, short* __restrict__ dst,
                                 int n8) {
    int t = blockIdx.x * 256 + threadIdx.x;
    if (t >= n8) return;
    const float4* p = (const float4*)(src + (size_t)t * 8);
    float4 a = p[0], b = p[1];
    uint4 o;
    o.x = f2bf_u(a.x) | (f2bf_u(a.y) << 16);
    o.y = f2bf_u(a.z) | (f2bf_u(a.w) << 16);
    o.z = f2bf_u(b.x) | (f2bf_u(b.y) << 16);
    o.w = f2bf_u(b.z) | (f2bf_u(b.w) << 16);
    *(uint4*)(dst + (size_t)t * 8) = o;
}

// ---- CSR-lite build: histogram -> single-block scan -> scatter ----
__global__ void hist_kernel(const int* __restrict__ ei, int* __restrict__ cnt) {
    int e = blockIdx.x * 256 + threadIdx.x;
    if (e < N_EDGES) atomicAdd(&cnt[ei[N_EDGES + e]], 1);
}

// int4-per-thread exclusive scan (n must be multiple of 4)
__global__ __launch_bounds__(1024)
void scan_kernel(const int* __restrict__ cnt, int* __restrict__ cursor, int n4) {
    __shared__ int wsum[16];
    __shared__ int s_carry;
    const int tid = threadIdx.x;
    const int lane = tid & 63, wid = tid >> 6;
    if (tid == 0) s_carry = 0;
    __syncthreads();
    for (int base = 0; base < n4; base += 1024) {
        int i = base + tid;
        int4 v = make_int4(0, 0, 0, 0);
        if (i < n4) v = ((const int4*)cnt)[i];
        int t0 = v.x, t1 = t0 + v.y, t2 = t1 + v.z, tot = t2 + v.w;
        int s = tot;
#pragma unroll
        for (int off = 1; off < 64; off <<= 1) {
            int sh = __shfl_up(s, off, 64);
            if (lane >= off) s += sh;
        }
        if (lane == 63) wsum[wid] = s;
        __syncthreads();
        if (tid < 16) {
            int t = wsum[tid];
            int sc = t;
#pragma unroll
            for (int off = 1; off < 16; off <<= 1) {
                int tt = __shfl_up(sc, off, 64);
                if (lane >= off) sc += tt;
            }
            wsum[tid] = sc - t;   // exclusive
        }
        __syncthreads();
        int excl = (s - tot) + wsum[wid] + s_carry;
        if (i < n4) {
            int4 o;
            o.x = excl; o.y = excl + t0; o.z = excl + t1; o.w = excl + t2;
            ((int4*)cursor)[i] = o;
        }
        __syncthreads();
        if (tid == 1023) s_carry = excl + tot;
        __syncthreads();
    }
}

__global__ void scatter_kernel(const int* __restrict__ ei, int* __restrict__ cursor,
                               int* __restrict__ eid) {
    int e = blockIdx.x * 256 + threadIdx.x;
    if (e >= N_EDGES) return;
    int d = ei[N_EDGES + e];
    int pos = atomicAdd(&cursor[d], 1);
    eid[pos] = e;
}

// ---- P/Q precompute: P = h @ We1[0:128] + be1, Q = h @ We1[128:256], bf16 out ----
__global__ __launch_bounds__(256, 4)
void pq_kernel(const short* __restrict__ h_bf, const short* __restrict__ pWe1,
               const float* __restrict__ be1,
               short* __restrict__ Pb, short* __restrict__ Qb) {
    __shared__ __align__(16) short sA[2 * 2048];
    const int tid = threadIdx.x;
    const int lane = tid & 63;
    const int w = tid >> 6;
    const int lc = lane & 15;
    const int quad = lane >> 4;
    const int n0 = blockIdx.x * 64;

#define STAGE_PQ(kc_, buf_) do {                                             \
        const int ko = (kc_) * 32 + (lane & 3) * 8;                          \
        const int row = w * 16 + (lane >> 2);                                \
        const int n = (n0 + row < N_NODES) ? n0 + row : N_NODES - 1;         \
        gl_lds16(h_bf + (size_t)n * 128 + ko, &sA[(buf_) * 2048 + w * 512]); \
    } while (0)

    STAGE_PQ(0, 0);
    const int ct0 = 2 * w, ct1 = 2 * w + 1;
    const int c0 = ct0 * 16 + lc, c1 = c0 + 16;

    floatx4 aP[4][2], aQ[4][2];
#pragma unroll
    for (int rt = 0; rt < 4; ++rt)
#pragma unroll
        for (int ct = 0; ct < 2; ++ct)
#pragma unroll
            for (int r = 0; r < 4; ++r) { aP[rt][ct][r] = 0.0f; aQ[rt][ct][r] = 0.0f; }

    for (int kc = 0; kc < 4; ++kc) {
        __syncthreads();
        if (kc < 3) STAGE_PQ(kc + 1, (kc + 1) & 1);
        const int buf = kc & 1;
        bf16x8 bp0 = *(const bf16x8*)&pWe1[((size_t)(kc * 8 + ct0) * 64 + lane) * 8];
        bf16x8 bp1 = *(const bf16x8*)&pWe1[((size_t)(kc * 8 + ct1) * 64 + lane) * 8];
        bf16x8 bq0 = *(const bf16x8*)&pWe1[((size_t)((kc + 4) * 8 + ct0) * 64 + lane) * 8];
        bf16x8 bq1 = *(const bf16x8*)&pWe1[((size_t)((kc + 4) * 8 + ct1) * 64 + lane) * 8];
#pragma unroll
        for (int rt = 0; rt < 4; ++rt) {
            bf16x8 a = *(const bf16x8*)&sA[buf * 2048 + (rt * 16 + lc) * 32 + quad * 8];
            aP[rt][0] = __builtin_amdgcn_mfma_f32_16x16x32_bf16(a, bp0, aP[rt][0], 0, 0, 0);
            aP[rt][1] = __builtin_amdgcn_mfma_f32_16x16x32_bf16(a, bp1, aP[rt][1], 0, 0, 0);
            aQ[rt][0] = __builtin_amdgcn_mfma_f32_16x16x32_bf16(a, bq0, aQ[rt][0], 0, 0, 0);
            aQ[rt][1] = __builtin_amdgcn_mfma_f32_16x16x32_bf16(a, bq1, aQ[rt][1], 0, 0, 0);
        }
    }
    float bb0 = be1[c0], bb1 = be1[c1];
#pragma unroll
    for (int rt = 0; rt < 4; ++rt)
#pragma unroll
        for (int r = 0; r < 4; ++r) {
            int n = n0 + rt * 16 + quad * 4 + r;
            if (n < N_NODES) {
                Pb[(size_t)n * 128 + c0] = f2bf(aP[rt][0][r] + bb0);
                Pb[(size_t)n * 128 + c1] = f2bf(aP[rt][1][r] + bb1);
                Qb[(size_t)n * 128 + c0] = f2bf(aQ[rt][0][r]);
                Qb[(size_t)n * 128 + c1] = f2bf(aQ[rt][1][r]);
            }
        }
#undef STAGE_PQ
}

// ==================== PRIMARY edge kernel (P/Q path) ====================
__global__ __launch_bounds__(256, 4)
void egnn_edge_pq(const short* __restrict__ Pb, const short* __restrict__ Qb,
                  const float* __restrict__ x,
                  const int* __restrict__ ei, const float* __restrict__ ea,
                  const int* __restrict__ eid_sorted,
                  const short* __restrict__ pWe1, const short* __restrict__ pWe2,
                  const short* __restrict__ pWx1,
                  const float* __restrict__ be2,
                  const float* __restrict__ bx1, const float* __restrict__ Wx2,
                  const float* __restrict__ bx2,
                  float* __restrict__ agg, float* __restrict__ dxb) {
    __shared__ __align__(16) short sT[128 * 128];
    __shared__ __align__(16) int s_src[128];
    __shared__ __align__(16) int s_dst[128];
    __shared__ float s_dir[384], sGate[128];

    const int tid = threadIdx.x;
    const int lane = tid & 63;
    const int w = tid >> 6;
    const int lc = lane & 15;
    const int quad = lane >> 4;

    int bix = blockIdx.x;
    int bid = (bix < 6248) ? (bix & 7) * 781 + (bix >> 3) : bix;
    const int e0 = bid * 128;

    // preamble: indices, dist, dir
    int e_reg = 0; float dist_reg = 0.0f;
    if (tid < 128) {
        e_reg = eid_sorted[e0 + tid];
        int s = ei[e_reg], d = ei[N_EDGES + e_reg];
        s_src[tid] = s; s_dst[tid] = d;
        float ddx = x[d * 3 + 0] - x[s * 3 + 0];
        float ddy = x[d * 3 + 1] - x[s * 3 + 1];
        float ddz = x[d * 3 + 2] - x[s * 3 + 2];
        float dot = ddx * ddx + ddy * ddy + ddz * ddz;
        dist_reg = sqrtf(dot + 1e-9f);
        float inv = 1.0f / (sqrtf(dot) + 1e-9f);
        s_dir[tid * 3 + 0] = ddx * inv;
        s_dir[tid * 3 + 1] = ddy * inv;
        s_dir[tid * 3 + 2] = ddz * inv;
        sGate[tid] = 0.0f;
    }
    __syncthreads();   // (A) src/dst visible

    // stage the ea|dist K=32 chunk into sT[0..4096)
    if (tid < 128) {
        const float4* p = (const float4*)&ea[(size_t)e_reg * 16];
        float4 a = p[0], b = p[1], c = p[2], d = p[3];
        uint4* dst = (uint4*)&sT[tid * 32];
        dst[0] = make_uint4(f2bf_u(a.x) | (f2bf_u(a.y) << 16),
                            f2bf_u(a.z) | (f2bf_u(a.w) << 16),
                            f2bf_u(b.x) | (f2bf_u(b.y) << 16),
                            f2bf_u(b.z) | (f2bf_u(b.w) << 16));
        dst[1] = make_uint4(f2bf_u(c.x) | (f2bf_u(c.y) << 16),
                            f2bf_u(c.z) | (f2bf_u(c.w) << 16),
                            f2bf_u(d.x) | (f2bf_u(d.y) << 16),
                            f2bf_u(d.z) | (f2bf_u(d.w) << 16));
        dst[2] = make_uint4(f2bf_u(dist_reg), 0u, 0u, 0u);
        dst[3] = make_uint4(0u, 0u, 0u, 0u);
    }

    const int ct0 = 2 * w, ct1 = 2 * w + 1;
    const int c0 = ct0 * 16 + lc, c1 = c0 + 16;

    // C-init: acc = P[src] + Q[dst] (layer-1 h-part, precomputed; be1 folded)
    floatx4 acc[8][2];
#pragma unroll
    for (int rt = 0; rt < 8; ++rt) {
        int4 ss = *(const int4*)&s_src[rt * 16 + quad * 4];
        int4 dd = *(const int4*)&s_dst[rt * 16 + quad * 4];
        acc[rt][0][0] = bf2f(Pb[(size_t)ss.x * 128 + c0]) + bf2f(Qb[(size_t)dd.x * 128 + c0]);
        acc[rt][0][1] = bf2f(Pb[(size_t)ss.y * 128 + c0]) + bf2f(Qb[(size_t)dd.y * 128 + c0]);
        acc[rt][0][2] = bf2f(Pb[(size_t)ss.z * 128 + c0]) + bf2f(Qb[(size_t)dd.z * 128 + c0]);
        acc[rt][0][3] = bf2f(Pb[(size_t)ss.w * 128 + c0]) + bf2f(Qb[(size_t)dd.w * 128 + c0]);
        acc[rt][1][0] = bf2f(Pb[(size_t)ss.x * 128 + c1]) + bf2f(Qb[(size_t)dd.x * 128 + c1]);
        acc[rt][1][1] = bf2f(Pb[(size_t)ss.y * 128 + c1]) + bf2f(Qb[(size_t)dd.y * 128 + c1]);
        acc[rt][1][2] = bf2f(Pb[(size_t)ss.z * 128 + c1]) + bf2f(Qb[(size_t)dd.z * 128 + c1]);
        acc[rt][1][3] = bf2f(Pb[(size_t)ss.w * 128 + c1]) + bf2f(Qb[(size_t)dd.w * 128 + c1]);
    }
    __syncthreads();   // (B) ea chunk staged

    // layer-1 remainder: single K=32 MFMA chunk (We1 rows 256..287 = chunk 8)
    {
        bf16x8 b0 = *(const bf16x8*)&pWe1[((size_t)(8 * 8 + ct0) * 64 + lane) * 8];
        bf16x8 b1 = *(const bf16x8*)&pWe1[((size_t)(8 * 8 + ct1) * 64 + lane) * 8];
#pragma unroll
        for (int rt = 0; rt < 8; ++rt) {
            bf16x8 a = *(const bf16x8*)&sT[(rt * 16 + lc) * 32 + quad * 8];
            acc[rt][0] = __builtin_amdgcn_mfma_f32_16x16x32_bf16(a, b0, acc[rt][0], 0, 0, 0);
            acc[rt][1] = __builtin_amdgcn_mfma_f32_16x16x32_bf16(a, b1, acc[rt][1], 0, 0, 0);
        }
    }
    __syncthreads();

    // epilogue 1: silu -> sT (bf16, swizzled); bias already folded into P
#pragma unroll
    for (int rt = 0; rt < 8; ++rt)
#pragma unroll
        for (int r = 0; r < 4; ++r) {
            int row = rt * 16 + quad * 4 + r;
            sT[sT_idx(row, c0)] = f2bf(silu_f(acc[rt][0][r]));
            sT[sT_idx(row, c1)] = f2bf(silu_f(acc[rt][1][r]));
        }
    __syncthreads();

    // ---- phi_e layer 2: m = t1 @ We2 + be2 ----
#pragma unroll
    for (int rt = 0; rt < 8; ++rt)
#pragma unroll
        for (int ct = 0; ct < 2; ++ct)
#pragma unroll
            for (int r = 0; r < 4; ++r) acc[rt][ct][r] = 0.0f;

    for (int kc = 0; kc < 4; ++kc) {
        bf16x8 b0 = *(const bf16x8*)&pWe2[((size_t)(kc * 8 + ct0) * 64 + lane) * 8];
        bf16x8 b1 = *(const bf16x8*)&pWe2[((size_t)(kc * 8 + ct1) * 64 + lane) * 8];
#pragma unroll
        for (int rt = 0; rt < 8; ++rt) {
            int kb = (kc * 4 + quad) ^ ((lc >> 1) & 7);
            bf16x8 a = *(const bf16x8*)&sT[(rt * 16 + lc) * 128 + kb * 8];
            acc[rt][0] = __builtin_amdgcn_mfma_f32_16x16x32_bf16(a, b0, acc[rt][0], 0, 0, 0);
            acc[rt][1] = __builtin_amdgcn_mfma_f32_16x16x32_bf16(a, b1, acc[rt][1], 0, 0, 0);
        }
    }
    {
        float bb0 = be2[c0], bb1 = be2[c1];
#pragma unroll
        for (int rt = 0; rt < 8; ++rt)
#pragma unroll
            for (int r = 0; r < 4; ++r) {
                acc[rt][0][r] += bb0;
                acc[rt][1][r] += bb1;
            }
    }
    __syncthreads();

    // write m -> sT (bf16, swizzled) for phi_x and the agg column-walk
#pragma unroll
    for (int rt = 0; rt < 8; ++rt)
#pragma unroll
        for (int r = 0; r < 4; ++r) {
            int row = rt * 16 + quad * 4 + r;
            sT[sT_idx(row, c0)] = f2bf(acc[rt][0][r]);
            sT[sT_idx(row, c1)] = f2bf(acc[rt][1][r]);
        }
    __syncthreads();

    // ---- phi_x ----
#pragma unroll
    for (int rt = 0; rt < 8; ++rt)
#pragma unroll
        for (int ct = 0; ct < 2; ++ct)
#pragma unroll
            for (int r = 0; r < 4; ++r) acc[rt][ct][r] = 0.0f;

    for (int kc = 0; kc < 4; ++kc) {
        bf16x8 b0 = *(const bf16x8*)&pWx1[((size_t)(kc * 8 + ct0) * 64 + lane) * 8];
        bf16x8 b1 = *(const bf16x8*)&pWx1[((size_t)(kc * 8 + ct1) * 64 + lane) * 8];
#pragma unroll
        for (int rt = 0; rt < 8; ++rt) {
            int kb = (kc * 4 + quad) ^ ((lc >> 1) & 7);
            bf16x8 a = *(const bf16x8*)&sT[(rt * 16 + lc) * 128 + kb * 8];
            acc[rt][0] = __builtin_amdgcn_mfma_f32_16x16x32_bf16(a, b0, acc[rt][0], 0, 0, 0);
            acc[rt][1] = __builtin_amdgcn_mfma_f32_16x16x32_bf16(a, b1, acc[rt][1], 0, 0, 0);
        }
    }

    // segmented agg scatter (column-walk over dst-sorted rows)
    {
        const int c = tid & 127;
        const int rb = (tid >> 7) * 64;
        float run = 0.0f;
        int cur = s_dst[rb];
        for (int r = rb; r < rb + 64; ++r) {
            int d = s_dst[r];
            if (d != cur) {
                atomicAdd(&agg[(size_t)cur * HDIM + c], run);
                run = 0.0f; cur = d;
            }
            run += bf2f(sT[sT_idx(r, c)]);
        }
        atomicAdd(&agg[(size_t)cur * HDIM + c], run);
    }

    // gate epilogue
    {
        float wx0 = Wx2[c0], wx1 = Wx2[c1];
        float bb0 = bx1[c0], bb1 = bx1[c1];
        float gp[8][4];
#pragma unroll
        for (int rt = 0; rt < 8; ++rt)
#pragma unroll
            for (int r = 0; r < 4; ++r)
                gp[rt][r] = silu_f(acc[rt][0][r] + bb0) * wx0 +
                            silu_f(acc[rt][1][r] + bb1) * wx1;
#pragma unroll
        for (int m = 1; m < 16; m <<= 1)
#pragma unroll
            for (int rt = 0; rt < 8; ++rt)
#pragma unroll
                for (int r = 0; r < 4; ++r)
                    gp[rt][r] += __shfl_xor(gp[rt][r], m, 64);
        if (lc == 0) {
#pragma unroll
            for (int rt = 0; rt < 8; ++rt)
#pragma unroll
                for (int r = 0; r < 4; ++r)
                    atomicAdd(&sGate[rt * 16 + quad * 4 + r], gp[rt][r]);
        }
    }
    __syncthreads();

    // segmented dx scatter
    if (tid < 48) {
        const int comp = tid % 3;
        const int ch = tid / 3;
        const float b2 = bx2[0];
        int r = ch * 8;
        float run = 0.0f;
        int cur = s_dst[r];
        for (int k = 0; k < 8; ++k, ++r) {
            int d = s_dst[r];
            if (d != cur) {
                atomicAdd(&dxb[(size_t)cur * 3 + comp], run);
                run = 0.0f; cur = d;
            }
            run += s_dir[r * 3 + comp] * (sGate[r] + b2);
        }
        atomicAdd(&dxb[(size_t)cur * 3 + comp], run);
    }
}

// ==================== FALLBACK edge kernel (round-4, proven) ====================
__global__ __launch_bounds__(256, 4)
void egnn_edge_v4(const short* __restrict__ h_bf, const float* __restrict__ x,
                  const int* __restrict__ ei, const float* __restrict__ ea,
                  const int* __restrict__ eid_sorted,
                  const short* __restrict__ pWe1, const short* __restrict__ pWe2,
                  const short* __restrict__ pWx1,
                  const float* __restrict__ be1, const float* __restrict__ be2,
                  const float* __restrict__ bx1, const float* __restrict__ Wx2,
                  const float* __restrict__ bx2,
                  float* __restrict__ agg, float* __restrict__ dxb) {
    __shared__ __align__(16) short sT[128 * 128];
    __shared__ int s_dst[128], s_eid[128];
    __shared__ float s_dist[128], s_dir[384], sGate[128];

    const int tid = threadIdx.x;
    const int lane = tid & 63;
    const int w = tid >> 6;
    const int lc = lane & 15;
    const int quad = lane >> 4;

    int bix = blockIdx.x;
    int bid = (bix < 6248) ? (bix & 7) * 781 + (bix >> 3) : bix;
    const int e0 = bid * 128;

    const int part = lane & 3;
    const int r0 = w * 32 + (lane >> 2);
    const int r1 = r0 + 16;
    const int eS0 = eid_sorted[e0 + r0], eS1 = eid_sorted[e0 + r1];
    const int es0 = ei[eS0], ed0 = ei[N_EDGES + eS0];
    const int es1 = ei[eS1], ed1 = ei[N_EDGES + eS1];

#define STAGE_H(kc_, buf_) do {                                              \
        const int ss = ((kc_) < 4);                                          \
        const int ko = ((kc_) & 3) * 32 + part * 8;                          \
        gl_lds16(h_bf + (size_t)(ss ? es0 : ed0) * 128 + ko,                 \
                 &sT[(buf_) * 4096 + w * 1024]);                             \
        gl_lds16(h_bf + (size_t)(ss ? es1 : ed1) * 128 + ko,                 \
                 &sT[(buf_) * 4096 + w * 1024 + 512]);                       \
    } while (0)

    STAGE_H(0, 0);

    if (tid < 128) {
        int e = eid_sorted[e0 + tid];
        s_eid[tid] = e;
        int s = ei[e], d = ei[N_EDGES + e];
        s_dst[tid] = d;
        float ddx = x[d * 3 + 0] - x[s * 3 + 0];
        float ddy = x[d * 3 + 1] - x[s * 3 + 1];
        float ddz = x[d * 3 + 2] - x[s * 3 + 2];
        float dot = ddx * ddx + ddy * ddy + ddz * ddz;
        s_dist[tid] = sqrtf(dot + 1e-9f);
        float inv = 1.0f / (sqrtf(dot) + 1e-9f);
        s_dir[tid * 3 + 0] = ddx * inv;
        s_dir[tid * 3 + 1] = ddy * inv;
        s_dir[tid * 3 + 2] = ddz * inv;
        sGate[tid] = 0.0f;
    }

    const int ct0 = 2 * w, ct1 = 2 * w + 1;
    const int c0 = ct0 * 16 + lc, c1 = c0 + 16;

    floatx4 acc[8][2];
#pragma unroll
    for (int rt = 0; rt < 8; ++rt)
#pragma unroll
        for (int ct = 0; ct < 2; ++ct)
#pragma unroll
            for (int r = 0; r < 4; ++r) acc[rt][ct][r] = 0.0f;

    for (int kc = 0; kc < 9; ++kc) {
        __syncthreads();
        if (kc < 7) {
            STAGE_H(kc + 1, (kc + 1) & 1);
        } else if (kc == 7) {
            if (tid < 128) {
                const float4* p = (const float4*)&ea[(size_t)s_eid[tid] * 16];
                float4 a = p[0], b = p[1], c = p[2], d = p[3];
                uint4* dst = (uint4*)&sT[0 * 4096 + tid * 32];
                dst[0] = make_uint4(f2bf_u(a.x) | (f2bf_u(a.y) << 16),
                                    f2bf_u(a.z) | (f2bf_u(a.w) << 16),
                                    f2bf_u(b.x) | (f2bf_u(b.y) << 16),
                                    f2bf_u(b.z) | (f2bf_u(b.w) << 16));
                dst[1] = make_uint4(f2bf_u(c.x) | (f2bf_u(c.y) << 16),
                                    f2bf_u(c.z) | (f2bf_u(c.w) << 16),
                                    f2bf_u(d.x) | (f2bf_u(d.y) << 16),
                                    f2bf_u(d.z) | (f2bf_u(d.w) << 16));
                dst[2] = make_uint4(f2bf_u(s_dist[tid]), 0u, 0u, 0u);
                dst[3] = make_uint4(0u, 0u, 0u, 0u);
            }
        }
        const int buf = kc & 1;
        bf16x8 b0 = *(const bf16x8*)&pWe1[((size_t)(kc * 8 + ct0) * 64 + lane) * 8];
        bf16x8 b1 = *(const bf16x8*)&pWe1[((size_t)(kc * 8 + ct1) * 64 + lane) * 8];
#pragma unroll
        for (int rt = 0; rt < 8; ++rt) {
            bf16x8 a = *(const bf16x8*)&sT[buf * 4096 + (rt * 16 + lc) * 32 + quad * 8];
            acc[rt][0] = __builtin_amdgcn_mfma_f32_16x16x32_bf16(a, b0, acc[rt][0], 0, 0, 0);
            acc[rt][1] = __builtin_amdgcn_mfma_f32_16x16x32_bf16(a, b1, acc[rt][1], 0, 0, 0);
        }
    }
    __syncthreads();

    {
        float bb0 = be1[c0], bb1 = be1[c1];
#pragma unroll
        for (int rt = 0; rt < 8; ++rt)
#pragma unroll
            for (int r = 0; r < 4; ++r) {
                int row = rt * 16 + quad * 4 + r;
                sT[sT_idx(row, c0)] = f2bf(silu_f(acc[rt][0][r] + bb0));
                sT[sT_idx(row, c1)] = f2bf(silu_f(acc[rt][1][r] + bb1));
            }
    }
    __syncthreads();

#pragma unroll
    for (int rt = 0; rt < 8; ++rt)
#pragma unroll
        for (int ct = 0; ct < 2; ++ct)
#pragma unroll
            for (int r = 0; r < 4; ++r) acc[rt][ct][r] = 0.0f;

    for (int kc = 0; kc < 4; ++kc) {
        bf16x8 b0 = *(const bf16x8*)&pWe2[((size_t)(kc * 8 + ct0) * 64 + lane) * 8];
        bf16x8 b1 = *(const bf16x8*)&pWe2[((size_t)(kc * 8 + ct1) * 64 + lane) * 8];
#pragma unroll
        for (int rt = 0; rt < 8; ++rt) {
            int kb = (kc * 4 + quad) ^ ((lc >> 1) & 7);
            bf16x8 a = *(const bf16x8*)&sT[(rt * 16 + lc) * 128 + kb * 8];
            acc[rt][0] = __builtin_amdgcn_mfma_f32_16x16x32_bf16(a, b0, acc[rt][0], 0, 0, 0);
            acc[rt][1] = __builtin_amdgcn_mfma_f32_16x16x32_bf16(a, b1, acc[rt][1], 0, 0, 0);
        }
    }
    {
        float bb0 = be2[c0], bb1 = be2[c1];
#pragma unroll
        for (int rt = 0; rt < 8; ++rt)
#pragma unroll
            for (int r = 0; r < 4; ++r) {
                acc[rt][0][r] += bb0;
                acc[rt][1][r] += bb1;
            }
    }
    __syncthreads();

#pragma unroll
    for (int rt = 0; rt < 8; ++rt)
#pragma unroll
        for (int r = 0; r < 4; ++r) {
            int row = rt * 16 + quad * 4 + r;
            sT[sT_idx(row, c0)] = f2bf(acc[rt][0][r]);
            sT[sT_idx(row, c1)] = f2bf(acc[rt][1][r]);
        }
    __syncthreads();

#pragma unroll
    for (int rt = 0; rt < 8; ++rt)
#pragma unroll
        for (int ct = 0; ct < 2; ++ct)
#pragma unroll
            for (int r = 0; r < 4; ++r) acc[rt][ct][r] = 0.0f;

    for (int kc = 0; kc < 4; ++kc) {
        bf16x8 b0 = *(const bf16x8*)&pWx1[((size_t)(kc * 8 + ct0) * 64 + lane) * 8];
        bf16x8 b1 = *(const bf16x8*)&pWx1[((size_t)(kc * 8 + ct1) * 64 + lane) * 8];
#pragma unroll
        for (int rt = 0; rt < 8; ++rt) {
            int kb = (kc * 4 + quad) ^ ((lc >> 1) & 7);
            bf16x8 a = *(const bf16x8*)&sT[(rt * 16 + lc) * 128 + kb * 8];
            acc[rt][0] = __builtin_amdgcn_mfma_f32_16x16x32_bf16(a, b0, acc[rt][0], 0, 0, 0);
            acc[rt][1] = __builtin_amdgcn_mfma_f32_16x16x32_bf16(a, b1, acc[rt][1], 0, 0, 0);
        }
    }

    {
        const int c = tid & 127;
        const int rb = (tid >> 7) * 64;
        float run = 0.0f;
        int cur = s_dst[rb];
        for (int r = rb; r < rb + 64; ++r) {
            int d = s_dst[r];
            if (d != cur) {
                atomicAdd(&agg[(size_t)cur * HDIM + c], run);
                run = 0.0f; cur = d;
            }
            run += bf2f(sT[sT_idx(r, c)]);
        }
        atomicAdd(&agg[(size_t)cur * HDIM + c], run);
    }

    {
        float wx0 = Wx2[c0], wx1 = Wx2[c1];
        float bb0 = bx1[c0], bb1 = bx1[c1];
        float gp[8][4];
#pragma unroll
        for (int rt = 0; rt < 8; ++rt)
#pragma unroll
            for (int r = 0; r < 4; ++r)
                gp[rt][r] = silu_f(acc[rt][0][r] + bb0) * wx0 +
                            silu_f(acc[rt][1][r] + bb1) * wx1;
#pragma unroll
        for (int m = 1; m < 16; m <<= 1)
#pragma unroll
            for (int rt = 0; rt < 8; ++rt)
#pragma unroll
                for (int r = 0; r < 4; ++r)
                    gp[rt][r] += __shfl_xor(gp[rt][r], m, 64);
        if (lc == 0) {
#pragma unroll
            for (int rt = 0; rt < 8; ++rt)
#pragma unroll
                for (int r = 0; r < 4; ++r)
                    atomicAdd(&sGate[rt * 16 + quad * 4 + r], gp[rt][r]);
        }
    }
    __syncthreads();

    if (tid < 48) {
        const int comp = tid % 3;
        const int ch = tid / 3;
        const float b2 = bx2[0];
        int r = ch * 8;
        float run = 0.0f;
        int cur = s_dst[r];
        for (int k = 0; k < 8; ++k, ++r) {
            int d = s_dst[r];
            if (d != cur) {
                atomicAdd(&dxb[(size_t)cur * 3 + comp], run);
                run = 0.0f; cur = d;
            }
            run += s_dir[r * 3 + comp] * (sGate[r] + b2);
        }
        atomicAdd(&dxb[(size_t)cur * 3 + comp], run);
    }
#undef STAGE_H
}

__global__ __launch_bounds__(256, 4)
void egnn_node_mfma(const short* __restrict__ h_bf, const float* __restrict__ h,
                    const float* __restrict__ x,
                    const float* __restrict__ agg, const float* __restrict__ dxb,
                    const short* __restrict__ pWh1, const short* __restrict__ pWh2,
                    const float* __restrict__ bh1, const float* __restrict__ bh2,
                    const float* __restrict__ ln_g, const float* __restrict__ ln_b,
                    float* __restrict__ hout, float* __restrict__ xout) {
    __shared__ __align__(16) short sT[64 * 128];
    __shared__ float sS1[64], sS2[64];

    const int tid = threadIdx.x;
    const int lane = tid & 63;
    const int w = tid >> 6;
    const int lc = lane & 15;
    const int quad = lane >> 4;
    const int n0 = blockIdx.x * 64;

#define STAGE_N(kc_, buf_) do {                                              \
        if ((kc_) < 4) {                                                     \
            const int ko = (kc_) * 32 + (lane & 3) * 8;                      \
            const int row = w * 16 + (lane >> 2);                            \
            const int n = (n0 + row < N_NODES) ? n0 + row : N_NODES - 1;     \
            gl_lds16(h_bf + (size_t)n * 128 + ko,                            \
                     &sT[(buf_) * 2048 + w * 512]);                          \
        } else {                                                             \
            const int srow = tid >> 2, prt = tid & 3;                        \
            const int n = (n0 + srow < N_NODES) ? n0 + srow : N_NODES - 1;   \
            const float4* p = (const float4*)&agg[(size_t)n * HDIM +         \
                                                  ((kc_) & 3) * 32 + prt * 8]; \
            float4 a = p[0], b = p[1];                                       \
            *(uint4*)&sT[(buf_) * 2048 + srow * 32 + prt * 8] =              \
                make_uint4(f2bf_u(a.x) | (f2bf_u(a.y) << 16),                \
                           f2bf_u(a.z) | (f2bf_u(a.w) << 16),                \
                           f2bf_u(b.x) | (f2bf_u(b.y) << 16),                \
                           f2bf_u(b.z) | (f2bf_u(b.w) << 16));               \
        }                                                                    \
    } while (0)

    STAGE_N(0, 0);
    if (tid < 64) { sS1[tid] = 0.0f; sS2[tid] = 0.0f; }

    const int ct0 = 2 * w, ct1 = 2 * w + 1;
    const int c0 = ct0 * 16 + lc, c1 = c0 + 16;

    floatx4 acc[4][2];
#pragma unroll
    for (int rt = 0; rt < 4; ++rt)
#pragma unroll
        for (int ct = 0; ct < 2; ++ct)
#pragma unroll
            for (int r = 0; r < 4; ++r) acc[rt][ct][r] = 0.0f;

    for (int kc = 0; kc < 8; ++kc) {
        __syncthreads();
        if (kc < 7) STAGE_N(kc + 1, (kc + 1) & 1);
        const int buf = kc & 1;
        bf16x8 b0 = *(const bf16x8*)&pWh1[((size_t)(kc * 8 + ct0) * 64 + lane) * 8];
        bf16x8 b1 = *(const bf16x8*)&pWh1[((size_t)(kc * 8 + ct1) * 64 + lane) * 8];
#pragma unroll
        for (int rt = 0; rt < 4; ++rt) {
            bf16x8 a = *(const bf16x8*)&sT[buf * 2048 + (rt * 16 + lc) * 32 + quad * 8];
            acc[rt][0] = __builtin_amdgcn_mfma_f32_16x16x32_bf16(a, b0, acc[rt][0], 0, 0, 0);
            acc[rt][1] = __builtin_amdgcn_mfma_f32_16x16x32_bf16(a, b1, acc[rt][1], 0, 0, 0);
        }
    }
    __syncthreads();

    {
        float bb0 = bh1[c0], bb1 = bh1[c1];
#pragma unroll
        for (int rt = 0; rt < 4; ++rt)
#pragma unroll
            for (int r = 0; r < 4; ++r) {
                int row = rt * 16 + quad * 4 + r;
                sT[sT_idx(row, c0)] = f2bf(silu_f(acc[rt][0][r] + bb0));
                sT[sT_idx(row, c1)] = f2bf(silu_f(acc[rt][1][r] + bb1));
            }
    }
    __syncthreads();

#pragma unroll
    for (int rt = 0; rt < 4; ++rt)
#pragma unroll
        for (int ct = 0; ct < 2; ++ct)
#pragma unroll
            for (int r = 0; r < 4; ++r) acc[rt][ct][r] = 0.0f;

    for (int kc = 0; kc < 4; ++kc) {
        bf16x8 b0 = *(const bf16x8*)&pWh2[((size_t)(kc * 8 + ct0) * 64 + lane) * 8];
        bf16x8 b1 = *(const bf16x8*)&pWh2[((size_t)(kc * 8 + ct1) * 64 + lane) * 8];
#pragma unroll
        for (int rt = 0; rt < 4; ++rt) {
            int kb = (kc * 4 + quad) ^ ((lc >> 1) & 7);
            bf16x8 a = *(const bf16x8*)&sT[(rt * 16 + lc) * 128 + kb * 8];
            acc[rt][0] = __builtin_amdgcn_mfma_f32_16x16x32_bf16(a, b0, acc[rt][0], 0, 0, 0);
            acc[rt][1] = __builtin_amdgcn_mfma_f32_16x16x32_bf16(a, b1, acc[rt][1], 0, 0, 0);
        }
    }

    {
        float bb0 = bh2[c0], bb1 = bh2[c1];
#pragma unroll
        for (int rt = 0; rt < 4; ++rt)
#pragma unroll
            for (int r = 0; r < 4; ++r) {
                int row = rt * 16 + quad * 4 + r;
                int n = n0 + row;
                int nc = (n < N_NODES) ? n : (N_NODES - 1);
                float v0 = acc[rt][0][r] + bb0 + h[(size_t)nc * HDIM + c0];
                float v1 = acc[rt][1][r] + bb1 + h[(size_t)nc * HDIM + c1];
                acc[rt][0][r] = v0;
                acc[rt][1][r] = v1;
                float s1 = v0 + v1;
                float s2 = v0 * v0 + v1 * v1;
#pragma unroll
                for (int m = 1; m < 16; m <<= 1) {
                    s1 += __shfl_xor(s1, m, 64);
                    s2 += __shfl_xor(s2, m, 64);
                }
                if (lc == 0) {
                    atomicAdd(&sS1[row], s1);
                    atomicAdd(&sS2[row], s2);
                }
            }
    }
    __syncthreads();
    {
        float g0 = ln_g[c0], g1 = ln_g[c1];
        float lb0 = ln_b[c0], lb1 = ln_b[c1];
#pragma unroll
        for (int rt = 0; rt < 4; ++rt)
#pragma unroll
            for (int r = 0; r < 4; ++r) {
                int row = rt * 16 + quad * 4 + r;
                int n = n0 + row;
                if (n < N_NODES) {
                    float mu = sS1[row] * (1.0f / 128.0f);
                    float var = sS2[row] * (1.0f / 128.0f) - mu * mu;
                    float rs = rsqrtf(var + 1e-5f);
                    hout[(size_t)n * HDIM + c0] = (acc[rt][0][r] - mu) * rs * g0 + lb0;
                    hout[(size_t)n * HDIM + c1] = (acc[rt][1][r] - mu) * rs * g1 + lb1;
                }
            }
    }

    if (tid < 192) {
        int n = n0 + tid / 3;
        int d = tid - (tid / 3) * 3;
        if (n < N_NODES) xout[(size_t)n * 3 + d] = x[(size_t)n * 3 + d] + dxb[(size_t)n * 3 + d];
    }
#undef STAGE_N
}

extern "C" void kernel_launch(void* const* d_in, const int* in_sizes, int n_in,
                              void* d_out, int out_size, void* d_ws, size_t ws_size,
                              hipStream_t stream) {
    (void)in_sizes; (void)n_in; (void)out_size;

    const float* h   = (const float*)d_in[0];
    const float* x   = (const float*)d_in[1];
    const int*   ei  = (const int*)d_in[2];
    const float* ea  = (const float*)d_in[3];
    const float* We1 = (const float*)d_in[4];
    const float* be1 = (const float*)d_in[5];
    const float* We2 = (const float*)d_in[6];
    const float* be2 = (const float*)d_in[7];
    const float* Wh1 = (const float*)d_in[8];
    const float* bh1 = (const float*)d_in[9];
    const float* Wh2 = (const float*)d_in[10];
    const float* bh2 = (const float*)d_in[11];
    const float* Wx1 = (const float*)d_in[12];
    const float* bx1 = (const float*)d_in[13];
    const float* Wx2 = (const float*)d_in[14];
    const float* bx2 = (const float*)d_in[15];
    const float* lng = (const float*)d_in[16];
    const float* lnb = (const float*)d_in[17];

    float* hout = (float*)d_out;
    float* xout = hout + (size_t)N_NODES * HDIM;

    const size_t CH = 8 * 64 * 8;
    const size_t oWe1 = 0, oWh1 = 17 * CH, oWh2 = 25 * CH;
    const size_t oWe2 = 9 * CH, oWx1 = 13 * CH;
    const size_t pwElems = 29 * CH;

    const size_t aggElems = (size_t)N_NODES * HDIM;
    const size_t dxbElems = (size_t)N_NODES * 3;
    const size_t aggB = aggElems * 4, dxbB = dxbElems * 4;
    const size_t pwB = pwElems * 2;
    const size_t hbB = (size_t)N_NODES * HDIM * 2;
    const size_t cntB = (size_t)N_NODES * 4;
    const size_t eidB = (size_t)N_EDGES * 4;

    char* ws = (char*)d_ws;
    const bool bigws = ws_size >= aggB + dxbB + pwB + hbB + 2 * cntB + eidB;

    float* agg; float* dxb; short* pw; short* h_bf; int* cnt; int* cursor; int* eid;
    if (bigws) {
        agg    = (float*)ws;
        dxb    = (float*)(ws + aggB);
        pw     = (short*)(ws + aggB + dxbB);
        h_bf   = (short*)(ws + aggB + dxbB + pwB);
        cnt    = (int*)(ws + aggB + dxbB + pwB + hbB);
        cursor = (int*)(ws + aggB + dxbB + pwB + hbB + cntB);
        eid    = (int*)(ws + aggB + dxbB + pwB + hbB + 2 * cntB);
    } else {
        pw     = (short*)ws;
        h_bf   = (short*)(ws + pwB);
        cnt    = (int*)(ws + pwB + hbB);
        cursor = (int*)(ws + pwB + hbB + cntB);
        eid    = (int*)(ws + pwB + hbB + 2 * cntB);
        agg    = (float*)d_out;    // aliasing safe: node blocks read their agg/
        dxb    = agg + aggElems;   // dxb rows before writing hout/xout rows
    }

    hipMemsetAsync(agg, 0, aggB, stream);
    hipMemsetAsync(dxb, 0, dxbB, stream);
    hipMemsetAsync(cnt, 0, cntB, stream);

    pack_bf16_kernel<<<(N_NODES * HDIM / 8 + 255) / 256, 256, 0, stream>>>(
        h, h_bf, N_NODES * HDIM / 8);
    pack_all_w<<<(29 * 512 + 255) / 256, 256, 0, stream>>>(We1, We2, Wx1, Wh1, Wh2, pw);

    hist_kernel<<<(N_EDGES + 255) / 256, 256, 0, stream>>>(ei, cnt);
    scan_kernel<<<1, 1024, 0, stream>>>(cnt, cursor, N_NODES / 4);
    scatter_kernel<<<(N_EDGES + 255) / 256, 256, 0, stream>>>(ei, cursor, eid);

    if (bigws) {
        // P/Q live in d_out (free scratch until node kernel writes hout/xout):
        // P = shorts [0, 6.4M), Q = shorts [6.4M, 12.8M)
        short* Pb = (short*)d_out;
        short* Qb = Pb + (size_t)N_NODES * HDIM;
        pq_kernel<<<(N_NODES + 63) / 64, 256, 0, stream>>>(h_bf, pw + oWe1, be1, Pb, Qb);
        egnn_edge_pq<<<N_EDGES / 128, 256, 0, stream>>>(
            Pb, Qb, x, ei, ea, eid, pw + oWe1, pw + oWe2, pw + oWx1,
            be2, bx1, Wx2, bx2, agg, dxb);
    } else {
        egnn_edge_v4<<<N_EDGES / 128, 256, 0, stream>>>(
            h_bf, x, ei, ea, eid, pw + oWe1, pw + oWe2, pw + oWx1,
            be1, be2, bx1, Wx2, bx2, agg, dxb);
    }

    egnn_node_mfma<<<(N_NODES + 63) / 64, 256, 0, stream>>>(
        h_bf, h, x, agg, dxb, pw + oWh1, pw + oWh2,
        bh1, bh2, lng, lnb, hout, xout);
}